// Round 22
// baseline (5185.362 us; speedup 1.0000x reference)
//
#include <hip/hip_runtime.h>
#include <hip/hip_bf16.h>

typedef __attribute__((ext_vector_type(8))) short bf16x8;
typedef __attribute__((ext_vector_type(4))) float f32x4;
typedef __hip_bfloat16 bf16;

#define ALPHA_F 0.42728713f
#define LN_EPS 1e-3f

__device__ __forceinline__ float silu_f(float x) { return x / (1.0f + __expf(-x)); }
__device__ __forceinline__ float mish_f(float x) {
  if (x > 20.0f) return x;
  float t = 1.0f + __expf(x);
  float t2 = t * t;
  return x * (t2 - 1.0f) / (t2 + 1.0f);
}
__device__ __forceinline__ unsigned short f2bfu(float x) {
  bf16 h = __float2bfloat16(x);
  return *(unsigned short*)&h;
}
__device__ __forceinline__ float bfu2f(unsigned short u) {
  unsigned int v = (unsigned int)u << 16;
  return *(float*)&v;
}

#define MFMA16(acc, a, b) \
  (acc) = __builtin_amdgcn_mfma_f32_16x16x32_bf16((a), (b), (acc), 0, 0, 0)

#define GLOAD_LDS16(gp, lp)                                                              \
  __builtin_amdgcn_global_load_lds((__attribute__((address_space(1))) void*)(void*)(gp), \
                                   (__attribute__((address_space(3))) void*)(void*)(lp), \
                                   16, 0, 0)

__global__ __launch_bounds__(1) void sentinel_k(float* __restrict__ o) { o[0] = 1.2345e7f; }

// ---------------- weight transpose body: W[K,N] f32 -> Wt[N,K] bf16 (+bias pack) -------
__device__ __forceinline__ void transpose_body(
    int tb, float* tile /* 32x33 LDS */,
    const float* wq, const float* wk, const float* wv, const float* wo,
    const float* f1, const float* f2, const float* sgf, const float* swg,
    const float* sh1, const float* scw,
    const float* bq, const float* bk, const float* bv,
    bf16* Wqkv, bf16* Wo, bf16* Wf1, bf16* Wf2, bf16* Wsgf, bf16* Wswg,
    bf16* Wsh1, bf16* Wsc, float* bqkv) {
  if (tb >= 10784) {  // bias pack
    int i = (tb - 10784) * 256 + threadIdx.x;
    if (i < 1024) bqkv[i] = bq[i];
    else if (i < 2048) bqkv[i] = bk[i - 1024];
    else bqkv[i] = bv[i - 2048];
    return;
  }
  const float* W;
  bf16* Wt;
  int K, N, b2;
  if (tb < 3072) {
    int m = tb >> 10;
    W = (m == 0) ? wq : ((m == 1) ? wk : wv);
    Wt = Wqkv + (size_t)m * 1024 * 1024;
    K = 1024; N = 1024; b2 = tb & 1023;
  } else if (tb < 4096)  { W = wo;  Wt = Wo;   K = 1024; N = 1024; b2 = tb - 3072; }
  else if (tb < 5632)    { W = f1;  Wt = Wf1;  K = 1024; N = 1536; b2 = tb - 4096; }
  else if (tb < 7168)    { W = f2;  Wt = Wf2;  K = 1536; N = 1024; b2 = tb - 5632; }
  else if (tb < 9216)    { W = sgf; Wt = Wsgf; K = 256;  N = 8192; b2 = tb - 7168; }
  else if (tb < 10240)   { W = swg; Wt = Wswg; K = 256;  N = 4096; b2 = tb - 9216; }
  else if (tb < 10752)   { W = sh1; Wt = Wsh1; K = 2048; N = 256;  b2 = tb - 10240; }
  else                   { W = scw; Wt = Wsc;  K = 1024; N = 32;   b2 = tb - 10752; }
  int ntx = N >> 5;
  int ty_ = b2 / ntx, tx_ = b2 - ty_ * ntx;
  int nb = tx_ * 32, kb = ty_ * 32;
  int tx = threadIdx.x & 31, ty = threadIdx.x >> 5;
#pragma unroll
  for (int i = 0; i < 4; ++i)
    tile[(ty + i * 8) * 33 + tx] = W[(size_t)(kb + ty + i * 8) * N + nb + tx];
  __syncthreads();
#pragma unroll
  for (int i = 0; i < 4; ++i)
    Wt[(size_t)(nb + ty + i * 8) * K + kb + tx] = __float2bfloat16(tile[tx * 33 + ty + i * 8]);
}

// ---------------- standalone transpose (layer-0 prologue) ------------------------------
__global__ __launch_bounds__(256) void transpose_layer(
    const float* wq, const float* wk, const float* wv, const float* wo,
    const float* f1, const float* f2, const float* sgf, const float* swg,
    const float* sh1, const float* scw,
    const float* bq, const float* bk, const float* bv,
    bf16* Wqkv, bf16* Wo, bf16* Wf1, bf16* Wf2, bf16* Wsgf, bf16* Wswg,
    bf16* Wsh1, bf16* Wsc, float* bqkv) {
  __shared__ float tile[32 * 33];
  transpose_body(blockIdx.x, tile, wq, wk, wv, wo, f1, f2, sgf, swg, sh1, scw,
                 bq, bk, bv, Wqkv, Wo, Wf1, Wf2, Wsgf, Wswg, Wsh1, Wsc, bqkv);
}

__global__ __launch_bounds__(256) void cvt_f32_bf16_k(const float* __restrict__ in,
                                                      bf16* __restrict__ out, long long n) {
  long long i = ((long long)blockIdx.x * 256 + threadIdx.x) * 4;
  if (i + 3 < n) {
    float4 v = *(const float4*)(in + i);
    out[i + 0] = __float2bfloat16(v.x);
    out[i + 1] = __float2bfloat16(v.y);
    out[i + 2] = __float2bfloat16(v.z);
    out[i + 3] = __float2bfloat16(v.w);
  }
}

// ---------------- megaA: QKV(1536) || c(128) || transpose-next(10796) ------------------
__global__ __launch_bounds__(256) void megaA(
    const bf16* __restrict__ xb,
    const bf16* __restrict__ Wqkv, const float* __restrict__ bqkv,
    bf16* __restrict__ qkvb,
    const bf16* __restrict__ Wsc, bf16* __restrict__ cbuf,
    int doT,
    const float* wq, const float* wk, const float* wv, const float* wo,
    const float* f1, const float* f2, const float* sgf, const float* swg,
    const float* sh1, const float* scw,
    const float* bq, const float* bk, const float* bv,
    bf16* WqkvN, bf16* WoN, bf16* Wf1N, bf16* Wf2N, bf16* WsgfN, bf16* WswgN,
    bf16* Wsh1N, bf16* WscN, float* bqkvN) {
  __shared__ __align__(128) short LB[8192];  // 16KB union
  const int bid = blockIdx.x;
  const int t = threadIdx.x;
  if (bid < 1536) {
    const int lane = t & 63, wave = t >> 6;
    int xcd = bid & 7, lid = bid >> 3;
    int swz = xcd * 192 + lid;
    int by = swz / 24, bx = swz - by * 24;
    int m0 = by << 7, n0 = bx << 7;
    int wr = wave >> 1, wc = wave & 1;
    int fr = lane & 15, fk = (lane >> 4) << 3;
    f32x4 acc[4][4] = {};
    int row0 = t >> 2, ko0 = (t & 3) << 3;
    const bf16* Ag0 = xb + (size_t)(m0 + row0) * 1024 + ko0;
    const bf16* Ag1 = xb + (size_t)(m0 + 64 + row0) * 1024 + ko0;
    const bf16* Bg0 = Wqkv + (size_t)(n0 + row0) * 1024 + ko0;
    const bf16* Bg1 = Wqkv + (size_t)(n0 + 64 + row0) * 1024 + ko0;
    const int rdA = (wr * 64 + fr) * 32 + fk;
    const int rdB = 4096 + (wc * 64 + fr) * 32 + fk;
    for (int kt = 0; kt < 32; ++kt) {
      int k0 = kt << 5;
      GLOAD_LDS16(Ag0 + k0, LB + wave * 512);
      GLOAD_LDS16(Ag1 + k0, LB + 2048 + wave * 512);
      GLOAD_LDS16(Bg0 + k0, LB + 4096 + wave * 512);
      GLOAD_LDS16(Bg1 + k0, LB + 6144 + wave * 512);
      __syncthreads();
      bf16x8 af[4], bfv[4];
#pragma unroll
      for (int a = 0; a < 4; ++a) af[a] = *(const bf16x8*)(LB + rdA + a * 512);
#pragma unroll
      for (int b = 0; b < 4; ++b) bfv[b] = *(const bf16x8*)(LB + rdB + b * 512);
#pragma unroll
      for (int a = 0; a < 4; ++a)
#pragma unroll
        for (int b = 0; b < 4; ++b) MFMA16(acc[a][b], af[a], bfv[b]);
      __syncthreads();
    }
    int lr = (lane >> 4) << 2, lc = lane & 15;
#pragma unroll
    for (int a = 0; a < 4; ++a)
#pragma unroll
      for (int b = 0; b < 4; ++b) {
        int col = n0 + wc * 64 + b * 16 + lc;
        float bv = bqkv[col];
#pragma unroll
        for (int j = 0; j < 4; ++j) {
          int rowi = m0 + wr * 64 + a * 16 + lr + j;
          qkvb[(size_t)rowi * 3072 + col] = __float2bfloat16(acc[a][b][j] + bv);
        }
      }
  } else if (bid < 1664) {
    const int lane = t & 63, w = t >> 6;
    const int fr = lane & 15, s4 = lane >> 4;
    const int row0 = ((bid - 1536) * 4 + w) * 16;
    f32x4 acc[2] = {};
    const bf16* Arow = xb + (size_t)(row0 + fr) * 1024 + s4 * 8;
    const bf16* B0 = Wsc + (size_t)fr * 1024 + s4 * 8;
    const bf16* B1 = Wsc + (size_t)(16 + fr) * 1024 + s4 * 8;
#pragma unroll 8
    for (int kt = 0; kt < 32; ++kt) {
      bf16x8 a = *(const bf16x8*)(Arow + kt * 32);
      bf16x8 b0 = *(const bf16x8*)(B0 + kt * 32);
      bf16x8 b1 = *(const bf16x8*)(B1 + kt * 32);
      acc[0] = __builtin_amdgcn_mfma_f32_16x16x32_bf16(a, b0, acc[0], 0, 0, 0);
      acc[1] = __builtin_amdgcn_mfma_f32_16x16x32_bf16(a, b1, acc[1], 0, 0, 0);
    }
#pragma unroll
    for (int n2 = 0; n2 < 2; ++n2)
#pragma unroll
      for (int j = 0; j < 4; ++j)
        cbuf[(size_t)(row0 + s4 * 4 + j) * 32 + n2 * 16 + fr] =
            __float2bfloat16(acc[n2][j]);
  } else {
    if (!doT) return;
    transpose_body(bid - 1664, (float*)LB, wq, wk, wv, wo, f1, f2, sgf, swg, sh1, scw,
                   bq, bk, bv, WqkvN, WoN, Wf1N, Wf2N, WsgfN, WswgN, Wsh1N, WscN, bqkvN);
  }
}

// ---------------- 64x64 bf16 MFMA GEMM, BK=64, counted-vmcnt 2-deep pipeline (T4) ------
// R21: the per-iter stall is the vmcnt(0) drain at __syncthreads (m97 ceiling). Here:
// stage buf^1 BEFORE computing buf; s_waitcnt vmcnt(4) (= exactly next tile's in-flight
// loads) + raw s_barrier; after MFMA, lgkmcnt(0)+s_barrier (reads done before overwrite,
// vmcnt untouched -> prefetch spans the barrier). LDS 32KB -> 5 blocks/CU.
// Ledger: stage(kt+1)=4 loads (8 out); vmcnt(4) retires tile kt's 4; last iter vmcnt(0).
template <int ACT, bool OUTBF16, bool BIAS>
__global__ __launch_bounds__(256) void gemm64p(const bf16* __restrict__ A,
                                               const bf16* __restrict__ Bt,
                                               const float* __restrict__ bias,
                                               float* __restrict__ Cf, bf16* __restrict__ Cb,
                                               int M, int N, int K) {
  __shared__ __align__(128) short As[8192];  // [buf][sub][64rows][32cols]
  __shared__ __align__(128) short Bs[8192];
  int t = threadIdx.x;
  int lane = t & 63, wave = t >> 6;
  // bijective XCD swizzle (m204)
  int nbx = N >> 6;
  int nwg = gridDim.x;
  int q = nwg >> 3, r = nwg & 7;
  int xcd = blockIdx.x & 7, lid = blockIdx.x >> 3;
  int swz = (xcd < r ? xcd * (q + 1) : r * (q + 1) + (xcd - r) * q) + lid;
  int by = swz / nbx, bx = swz - by * nbx;
  int m0 = by << 6, n0 = bx << 6;
  int fr = lane & 15;
  int fk = (lane >> 4) << 3;

  f32x4 acc[4] = {};  // AR=1, AC=4

  int row0 = t >> 2, ko0 = (t & 3) << 3;
  const bf16* Ag0 = A + (size_t)(m0 + row0) * K + ko0;
  const bf16* Bg0 = Bt + (size_t)(n0 + row0) * K + ko0;

  auto stageTo = [&](int buf, int k0) {
#pragma unroll
    for (int s = 0; s < 2; ++s) {
      GLOAD_LDS16(Ag0 + k0 + s * 32, As + buf * 4096 + s * 2048 + wave * 512);
      GLOAD_LDS16(Bg0 + k0 + s * 32, Bs + buf * 4096 + s * 2048 + wave * 512);
    }
  };

  int nk = K >> 6;
  const int rdA = (wave * 16 + fr) * 32 + fk;  // 16 rows/wave
  const int rdB = fr * 32 + fk;

  stageTo(0, 0);  // 4 loads in flight
  for (int kt = 0; kt < nk; ++kt) {
    int cur = kt & 1;
    if (kt + 1 < nk) {
      stageTo(cur ^ 1, (kt + 1) << 6);                 // +4 -> 8 in flight
      asm volatile("s_waitcnt vmcnt(4)" ::: "memory"); // retire tile kt's 4
    } else {
      asm volatile("s_waitcnt vmcnt(0)" ::: "memory");
    }
    __builtin_amdgcn_s_barrier();  // buf[cur] resident for all waves
    bf16x8 af[2], bfv[4][2];
#pragma unroll
    for (int h = 0; h < 2; ++h) {
      af[h] = *(const bf16x8*)(As + cur * 4096 + h * 2048 + rdA);
#pragma unroll
      for (int b = 0; b < 4; ++b)
        bfv[b][h] = *(const bf16x8*)(Bs + cur * 4096 + h * 2048 + rdB + b * 512);
    }
#pragma unroll
    for (int h = 0; h < 2; ++h)
#pragma unroll
      for (int b = 0; b < 4; ++b) MFMA16(acc[b], af[h], bfv[b][h]);
    asm volatile("s_waitcnt lgkmcnt(0)" ::: "memory");  // my ds_reads done (vmcnt untouched)
    __builtin_amdgcn_s_barrier();  // all reads done before buf[cur] overwritten next iter
  }
  int lr = (lane >> 4) << 2;
  int lc = lane & 15;
#pragma unroll
  for (int b = 0; b < 4; ++b) {
    int col = n0 + b * 16 + lc;
    float bv = 0.0f;
    if constexpr (BIAS) bv = bias[col];
#pragma unroll
    for (int j = 0; j < 4; ++j) {
      int rowi = m0 + wave * 16 + lr + j;
      float v = acc[b][j] + bv;
      if constexpr (ACT == 1) v = silu_f(v);
      if constexpr (ACT == 2) v = mish_f(v);
      if constexpr (OUTBF16) Cb[(size_t)rowi * N + col] = __float2bfloat16(v);
      else Cf[(size_t)rowi * N + col] = v;
    }
  }
}

// ---------------- 1-wave 16x16-tile GEMM, direct-from-global ---------------------------
template <int ACT>
__global__ __launch_bounds__(64) void gemm_wave16(const bf16* __restrict__ A,
                                                  const bf16* __restrict__ Bt,
                                                  const float* __restrict__ bias,
                                                  float* __restrict__ Cf,
                                                  int N, int K) {
  const int lane = threadIdx.x;
  const int fr = lane & 15, s4 = lane >> 4;
  const int ncols = N >> 4;
  const int rb = blockIdx.x / ncols, cb = blockIdx.x - rb * ncols;
  const int row0 = rb << 4, col0 = cb << 4;
  f32x4 acc = {};
  const bf16* Arow = A + (size_t)(row0 + fr) * K + s4 * 8;
  const bf16* Brow = Bt + (size_t)(col0 + fr) * K + s4 * 8;
  const int nk = K >> 5;
#pragma unroll 8
  for (int kt = 0; kt < nk; ++kt) {
    bf16x8 a = *(const bf16x8*)(Arow + kt * 32);
    bf16x8 b = *(const bf16x8*)(Brow + kt * 32);
    acc = __builtin_amdgcn_mfma_f32_16x16x32_bf16(a, b, acc, 0, 0, 0);
  }
#pragma unroll
  for (int j = 0; j < 4; ++j) {
    int col = col0 + fr;
    float v = acc[j] + bias[col];
    if constexpr (ACT == 1) v = silu_f(v);
    Cf[(size_t)(row0 + s4 * 4 + j) * N + col] = v;
  }
}

// ---------------- LN over 256 cols ----------------------------------------------------
__global__ __launch_bounds__(256) void ln256_kernel(const float* __restrict__ hpre,
                                                    const float* __restrict__ gam,
                                                    const float* __restrict__ bet,
                                                    bf16* __restrict__ hb) {
  __shared__ float rsm[4], rs2[4], st2[2];
  int t = threadIdx.x, row = blockIdx.x;
  float sv = hpre[(size_t)row * 256 + t];
  float s = sv, s2 = sv * sv;
#pragma unroll
  for (int o = 32; o > 0; o >>= 1) { s += __shfl_down(s, o); s2 += __shfl_down(s2, o); }
  if ((t & 63) == 0) { rsm[t >> 6] = s; rs2[t >> 6] = s2; }
  __syncthreads();
  if (t == 0) {
    float a = rsm[0] + rsm[1] + rsm[2] + rsm[3];
    float b2 = rs2[0] + rs2[1] + rs2[2] + rs2[3];
    float m = a * (1.0f / 256.0f);
    st2[0] = m;
    st2[1] = rsqrtf(b2 * (1.0f / 256.0f) - m * m + LN_EPS);
  }
  __syncthreads();
  float y = (sv - st2[0]) * st2[1] * gam[t] + bet[t];
  hb[(size_t)row * 256 + t] = __float2bfloat16(y);
}

// ---------------- LN over 8192 cols ----------------------------------------------------
__global__ __launch_bounds__(1024) void ln8192_kernel(const float* __restrict__ gpre,
                                                      const float* __restrict__ gam,
                                                      const float* __restrict__ bet,
                                                      bf16* __restrict__ gb) {
  __shared__ float rsm[16], rs2[16], st2[2];
  int t = threadIdx.x, row = blockIdx.x;
  const float* p = gpre + (size_t)row * 8192;
  float v[8];
  float s = 0.0f, s2 = 0.0f;
#pragma unroll
  for (int i = 0; i < 8; ++i) {
    v[i] = p[t + i * 1024];
    s += v[i];
    s2 += v[i] * v[i];
  }
#pragma unroll
  for (int o = 32; o > 0; o >>= 1) { s += __shfl_down(s, o); s2 += __shfl_down(s2, o); }
  int lane = t & 63, w = t >> 6;
  if (lane == 0) { rsm[w] = s; rs2[w] = s2; }
  __syncthreads();
  if (t == 0) {
    float a = 0.0f, b2 = 0.0f;
#pragma unroll
    for (int i = 0; i < 16; ++i) { a += rsm[i]; b2 += rs2[i]; }
    float m = a * (1.0f / 8192.0f);
    st2[0] = m;
    st2[1] = rsqrtf(b2 * (1.0f / 8192.0f) - m * m + LN_EPS);
  }
  __syncthreads();
  float m = st2[0], r = st2[1];
#pragma unroll
  for (int i = 0; i < 8; ++i) {
    int n = t + i * 1024;
    gb[(size_t)row * 8192 + n] = __float2bfloat16((v[i] - m) * r * gam[n] + bet[n]);
  }
}

// ---------------- residual + LN over 1024 cols (f32 base, bf16 delta) ------------------
__global__ __launch_bounds__(256) void ln_residual_kernel(const float* __restrict__ base,
                                                          const bf16* __restrict__ delta,
                                                          const float* __restrict__ gam,
                                                          const float* __restrict__ bet,
                                                          float* __restrict__ outf,
                                                          bf16* __restrict__ outb) {
  __shared__ float rsm[4], rs2[4], st2[2];
  int t = threadIdx.x, row = blockIdx.x;
  float4 bv = ((const float4*)(base + (size_t)row * 1024))[t];
  ushort4 du = ((const ushort4*)(delta + (size_t)row * 1024))[t];
  float4 v;
  v.x = bv.x + bfu2f(du.x) * ALPHA_F;
  v.y = bv.y + bfu2f(du.y) * ALPHA_F;
  v.z = bv.z + bfu2f(du.z) * ALPHA_F;
  v.w = bv.w + bfu2f(du.w) * ALPHA_F;
  float s = v.x + v.y + v.z + v.w;
  float s2 = v.x * v.x + v.y * v.y + v.z * v.z + v.w * v.w;
#pragma unroll
  for (int o = 32; o > 0; o >>= 1) { s += __shfl_down(s, o); s2 += __shfl_down(s2, o); }
  if ((t & 63) == 0) { rsm[t >> 6] = s; rs2[t >> 6] = s2; }
  __syncthreads();
  if (t == 0) {
    float a = rsm[0] + rsm[1] + rsm[2] + rsm[3];
    float b2 = rs2[0] + rs2[1] + rs2[2] + rs2[3];
    float m = a * (1.0f / 1024.0f);
    st2[0] = m;
    st2[1] = rsqrtf(b2 * (1.0f / 1024.0f) - m * m + LN_EPS);
  }
  __syncthreads();
  float m = st2[0], r = st2[1];
  float4 g4 = ((const float4*)gam)[t];
  float4 b4 = ((const float4*)bet)[t];
  float4 y;
  y.x = (v.x - m) * r * g4.x + b4.x;
  y.y = (v.y - m) * r * g4.y + b4.y;
  y.z = (v.z - m) * r * g4.z + b4.z;
  y.w = (v.w - m) * r * g4.w + b4.w;
  ((float4*)(outf + (size_t)row * 1024))[t] = y;
  ushort4 o4;
  o4.x = f2bfu(y.x); o4.y = f2bfu(y.y); o4.z = f2bfu(y.z); o4.w = f2bfu(y.w);
  ((ushort4*)(outb + (size_t)row * 1024))[t] = o4;
}

// ---------------- MFMA fused attention per (b,h) ---------------------------------------
__global__ __launch_bounds__(256) void attn_kernel(const bf16* __restrict__ qkv,
                                                   const bf16* __restrict__ sw,
                                                   bf16* __restrict__ avb) {
  __shared__ __align__(16) short Vt[32 * 72];
  __shared__ __align__(16) short Pl[64 * 72];
  const int t = threadIdx.x, lane = t & 63, w = t >> 6;
  const int fr = lane & 15, s4 = lane >> 4;
  const int bh = blockIdx.x, b = bh >> 5, h = bh & 31;
  const size_t qb = (size_t)b * 64 * 3072 + h * 32;
  {
    int k = t >> 2, d0 = (t & 3) * 8;
    bf16x8 v = *(const bf16x8*)(qkv + qb + (size_t)k * 3072 + 2048 + d0);
#pragma unroll
    for (int i = 0; i < 8; ++i) Vt[(d0 + i) * 72 + k] = v[i];
  }
  f32x4 acc[4] = {};
  {
    bf16x8 aq = *(const bf16x8*)(qkv + qb + (size_t)(16 * w + fr) * 3072 + s4 * 8);
#pragma unroll
    for (int n = 0; n < 4; ++n) {
      bf16x8 bk = *(const bf16x8*)(qkv + qb + (size_t)(n * 16 + fr) * 3072 + 1024 + s4 * 8);
      acc[n] = __builtin_amdgcn_mfma_f32_16x16x32_bf16(aq, bk, acc[n], 0, 0, 0);
    }
  }
  const bf16* swp = sw + (size_t)bh * 4096;
  float rinv[4];
#pragma unroll
  for (int j = 0; j < 4; ++j) {
    int q = 16 * w + s4 * 4 + j;
    float pv[4];
    float mx = -1e30f;
#pragma unroll
    for (int n = 0; n < 4; ++n) {
      float v = acc[n][j] * 0.17677669529663687f +
                __bfloat162float(swp[q * 64 + n * 16 + fr]);
      pv[n] = v;
      mx = fmaxf(mx, v);
    }
    mx = fmaxf(mx, __shfl_xor(mx, 1));
    mx = fmaxf(mx, __shfl_xor(mx, 2));
    mx = fmaxf(mx, __shfl_xor(mx, 4));
    mx = fmaxf(mx, __shfl_xor(mx, 8));
    float sum = 0.0f;
#pragma unroll
    for (int n = 0; n < 4; ++n) {
      float e = __expf(pv[n] - mx);
      sum += e;
      ((bf16*)Pl)[q * 72 + n * 16 + fr] = __float2bfloat16(e);
    }
    sum += __shfl_xor(sum, 1);
    sum += __shfl_xor(sum, 2);
    sum += __shfl_xor(sum, 4);
    sum += __shfl_xor(sum, 8);
    rinv[j] = 1.0f / sum;
  }
  __syncthreads();
  f32x4 acc2[2] = {};
#pragma unroll
  for (int kt = 0; kt < 2; ++kt) {
    bf16x8 ap = *(const bf16x8*)(Pl + (16 * w + fr) * 72 + kt * 32 + s4 * 8);
#pragma unroll
    for (int n2 = 0; n2 < 2; ++n2) {
      bf16x8 bv = *(const bf16x8*)(Vt + (n2 * 16 + fr) * 72 + kt * 32 + s4 * 8);
      acc2[n2] = __builtin_amdgcn_mfma_f32_16x16x32_bf16(ap, bv, acc2[n2], 0, 0, 0);
    }
  }
#pragma unroll
  for (int n2 = 0; n2 < 2; ++n2) {
#pragma unroll
    for (int j = 0; j < 4; ++j) {
      int q = 16 * w + s4 * 4 + j;
      int d = n2 * 16 + fr;
      avb[(size_t)(b * 64 + q) * 1024 + h * 32 + d] =
          __float2bfloat16(acc2[n2][j] * rinv[j]);
    }
  }
}

extern "C" void kernel_launch(void* const* d_in, const int* in_sizes, int n_in,
                              void* d_out, int out_size, void* d_ws, size_t ws_size,
                              hipStream_t stream) {
  const float* x_in   = (const float*)d_in[0];
  const float* wq_w   = (const float*)d_in[1];
  const float* wq_b   = (const float*)d_in[2];
  const float* wk_w   = (const float*)d_in[3];
  const float* wk_b   = (const float*)d_in[4];
  const float* wv_w   = (const float*)d_in[5];
  const float* wv_b   = (const float*)d_in[6];
  const float* wo_w   = (const float*)d_in[7];
  const float* wo_b   = (const float*)d_in[8];
  const float* sc_w   = (const float*)d_in[9];
  const float* sh1_w  = (const float*)d_in[10];
  const float* sh1_b  = (const float*)d_in[11];
  const float* sln1_g = (const float*)d_in[12];
  const float* sln1_b = (const float*)d_in[13];
  const float* sgf_w  = (const float*)d_in[14];
  const float* sgf_b  = (const float*)d_in[15];
  const float* sln2_g = (const float*)d_in[16];
  const float* sln2_b = (const float*)d_in[17];
  const float* swg_w  = (const float*)d_in[18];
  const float* ffn1_w = (const float*)d_in[19];
  const float* ffn1_b = (const float*)d_in[20];
  const float* ffn2_w = (const float*)d_in[21];
  const float* ffn2_b = (const float*)d_in[22];
  const float* n1_g   = (const float*)d_in[23];
  const float* n1_b   = (const float*)d_in[24];
  const float* n2_g   = (const float*)d_in[25];
  const float* n2_b   = (const float*)d_in[26];

  char* ws = (char*)d_ws;
  size_t off = 0;
  auto alloc = [&](size_t bytes) -> void* {
    void* p = ws + off;
    off += (bytes + 255) & ~(size_t)255;
    return p;
  };
  bf16*  xb    = (bf16*)alloc(8192ULL * 1024 * 2);
  float* P0    = (float*)alloc(8192ULL * 1024 * 4);
  float* P1    = (float*)alloc(8192ULL * 1024 * 4);
  bf16*  dT    = (bf16*)alloc(8192ULL * 1024 * 2);
  // double-buffered transposed weights (buf = layer & 1)
  bf16*  WqkvB = (bf16*)alloc(2ULL * 3072 * 1024 * 2);
  float* bqkvB = (float*)alloc(2ULL * 3072 * 4);
  bf16*  WoB   = (bf16*)alloc(2ULL * 1024 * 1024 * 2);
  bf16*  Wf1B  = (bf16*)alloc(2ULL * 1536 * 1024 * 2);
  bf16*  Wf2B  = (bf16*)alloc(2ULL * 1024 * 1536 * 2);
  bf16*  WsgfB = (bf16*)alloc(2ULL * 8192 * 256 * 2);
  bf16*  WswgB = (bf16*)alloc(2ULL * 4096 * 256 * 2);
  bf16*  Wsh1B = (bf16*)alloc(2ULL * 256 * 2048 * 2);
  bf16*  WscB  = (bf16*)alloc(2ULL * 32 * 1024 * 2);
  bf16*  qkvb  = (bf16*)alloc(8192ULL * 3072 * 2);
  bf16*  cbuf  = (bf16*)alloc(8192ULL * 32 * 2);
  float* hpre  = (float*)alloc(128ULL * 256 * 4);
  bf16*  hbb   = (bf16*)alloc(128ULL * 256 * 2);
  float* gpre  = (float*)alloc(128ULL * 8192 * 4);
  bf16*  gbb   = (bf16*)alloc(128ULL * 8192 * 2);
  bf16*  swb   = (bf16*)alloc(4096ULL * 4096 * 2);
  bf16*  avb   = (bf16*)alloc(8192ULL * 1024 * 2);
  bf16*  out1b = (bf16*)alloc(8192ULL * 1024 * 2);
  bf16*  f1b   = (bf16*)alloc(8192ULL * 1536 * 2);
  if (off > ws_size) {
    sentinel_k<<<1, 1, 0, stream>>>((float*)d_out);
    return;
  }

  cvt_f32_bf16_k<<<8192, 256, 0, stream>>>(x_in, xb, 8192LL * 1024);
  // prologue: transpose layer 0 into buf 0
  transpose_layer<<<10796, 256, 0, stream>>>(
      wq_w, wk_w, wv_w, wo_w, ffn1_w, ffn2_w, sgf_w, swg_w, sh1_w, sc_w,
      wq_b, wk_b, wv_b,
      WqkvB, WoB, Wf1B, Wf2B, WsgfB, WswgB, Wsh1B, WscB, bqkvB);

  for (int l = 0; l < 15; ++l) {
    const int cur = l & 1, nxt = cur ^ 1;
    const int lp = l + 1;
    bf16*  Wqkv = WqkvB + (size_t)cur * 3072 * 1024;
    float* bqkv = bqkvB + (size_t)cur * 3072;
    bf16*  Wo   = WoB   + (size_t)cur * 1024 * 1024;
    bf16*  Wf1  = Wf1B  + (size_t)cur * 1536 * 1024;
    bf16*  Wf2  = Wf2B  + (size_t)cur * 1024 * 1536;
    bf16*  Wsgf = WsgfB + (size_t)cur * 8192 * 256;
    bf16*  Wswg = WswgB + (size_t)cur * 4096 * 256;
    bf16*  Wsh1 = Wsh1B + (size_t)cur * 256 * 2048;
    bf16*  Wsc  = WscB  + (size_t)cur * 32 * 1024;

    const float* xc = (l == 0) ? x_in : ((l & 1) ? P0 : P1);
    float* Pout = (l & 1) ? P1 : P0;

    // megaA: QKV || c || transpose(l+1)
    megaA<<<12460, 256, 0, stream>>>(
        xb, Wqkv, bqkv, qkvb, Wsc, cbuf, (l < 14) ? 1 : 0,
        wq_w + (size_t)lp * 1048576, wk_w + (size_t)lp * 1048576,
        wv_w + (size_t)lp * 1048576, wo_w + (size_t)lp * 1048576,
        ffn1_w + (size_t)lp * 1024 * 1536, ffn2_w + (size_t)lp * 1536 * 1024,
        sgf_w + (size_t)lp * 256 * 8192, swg_w + (size_t)lp * 256 * 4096,
        sh1_w + (size_t)lp * 2048 * 256, sc_w + (size_t)lp * 1024 * 32,
        wq_b + (size_t)lp * 1024, wk_b + (size_t)lp * 1024, wv_b + (size_t)lp * 1024,
        WqkvB + (size_t)nxt * 3072 * 1024, WoB + (size_t)nxt * 1024 * 1024,
        Wf1B + (size_t)nxt * 1536 * 1024, Wf2B + (size_t)nxt * 1024 * 1536,
        WsgfB + (size_t)nxt * 8192 * 256, WswgB + (size_t)nxt * 4096 * 256,
        Wsh1B + (size_t)nxt * 256 * 2048, WscB + (size_t)nxt * 32 * 1024,
        bqkvB + (size_t)nxt * 3072);
    // smolgen chain (MFMA wave16 path)
    gemm_wave16<1><<<128, 64, 0, stream>>>(cbuf, Wsh1, sh1_b + l * 256, hpre, 256, 2048);
    ln256_kernel<<<128, 256, 0, stream>>>(hpre, sln1_g + l * 256, sln1_b + l * 256, hbb);
    gemm_wave16<1><<<4096, 64, 0, stream>>>(hbb, Wsgf, sgf_b + (size_t)l * 8192, gpre,
                                            8192, 256);
    ln8192_kernel<<<128, 1024, 0, stream>>>(gpre, sln2_g + (size_t)l * 8192,
                                            sln2_b + (size_t)l * 8192, gbb);
    // sw gemm (counted-vmcnt pipeline)
    gemm64p<0, true, false><<<4096, 256, 0, stream>>>(gbb, Wswg, nullptr, nullptr,
                                                      swb, 4096, 4096, 256);
    // attention
    attn_kernel<<<4096, 256, 0, stream>>>(qkvb, swb, avb);
    // output projection + LN1
    gemm64p<0, true, true><<<2048, 256, 0, stream>>>(avb, Wo, wo_b + l * 1024,
                                                     nullptr, dT, 8192, 1024, 1024);
    ln_residual_kernel<<<8192, 256, 0, stream>>>(xc, dT, n1_g + l * 1024, n1_b + l * 1024,
                                                 Pout, out1b);
    // FFN + LN2
    gemm64p<2, true, true><<<3072, 256, 0, stream>>>(out1b, Wf1, ffn1_b + l * 1536,
                                                     nullptr, f1b, 8192, 1536, 1024);
    gemm64p<0, true, true><<<2048, 256, 0, stream>>>(f1b, Wf2, ffn2_b + l * 1024,
                                                     nullptr, dT, 8192, 1024, 1536);
    float* xnext = (l == 14) ? (float*)d_out : Pout;
    ln_residual_kernel<<<8192, 256, 0, stream>>>(Pout, dT, n2_g + l * 1024, n2_b + l * 1024,
                                                 xnext, xb);
  }
}

// Round 24
// 5171.730 us; speedup vs baseline: 1.0026x; 1.0026x over previous
//
#include <hip/hip_runtime.h>
#include <hip/hip_bf16.h>

typedef __attribute__((ext_vector_type(8))) short bf16x8;
typedef __attribute__((ext_vector_type(4))) float f32x4;
typedef __hip_bfloat16 bf16;

#define ALPHA_F 0.42728713f
#define LN_EPS 1e-3f

__device__ __forceinline__ float silu_f(float x) { return x / (1.0f + __expf(-x)); }
__device__ __forceinline__ float mish_f(float x) {
  if (x > 20.0f) return x;
  float t = 1.0f + __expf(x);
  float t2 = t * t;
  return x * (t2 - 1.0f) / (t2 + 1.0f);
}
__device__ __forceinline__ unsigned short f2bfu(float x) {
  bf16 h = __float2bfloat16(x);
  return *(unsigned short*)&h;
}
__device__ __forceinline__ float bfu2f(unsigned short u) {
  unsigned int v = (unsigned int)u << 16;
  return *(float*)&v;
}

#define MFMA16(acc, a, b) \
  (acc) = __builtin_amdgcn_mfma_f32_16x16x32_bf16((a), (b), (acc), 0, 0, 0)

#define GLOAD_LDS16(gp, lp)                                                              \
  __builtin_amdgcn_global_load_lds((__attribute__((address_space(1))) void*)(void*)(gp), \
                                   (__attribute__((address_space(3))) void*)(void*)(lp), \
                                   16, 0, 0)

__global__ __launch_bounds__(1) void sentinel_k(float* __restrict__ o) { o[0] = 1.2345e7f; }

// ---------------- weight transpose body: W[K,N] f32 -> Wt[N,K] bf16 (+bias pack) -------
__device__ __forceinline__ void transpose_body(
    int tb, float* tile /* 32x33 LDS */,
    const float* wq, const float* wk, const float* wv, const float* wo,
    const float* f1, const float* f2, const float* sgf, const float* swg,
    const float* sh1, const float* scw,
    const float* bq, const float* bk, const float* bv,
    bf16* Wqkv, bf16* Wo, bf16* Wf1, bf16* Wf2, bf16* Wsgf, bf16* Wswg,
    bf16* Wsh1, bf16* Wsc, float* bqkv) {
  if (tb >= 10784) {  // bias pack
    int i = (tb - 10784) * 256 + threadIdx.x;
    if (i < 1024) bqkv[i] = bq[i];
    else if (i < 2048) bqkv[i] = bk[i - 1024];
    else bqkv[i] = bv[i - 2048];
    return;
  }
  const float* W;
  bf16* Wt;
  int K, N, b2;
  if (tb < 3072) {
    int m = tb >> 10;
    W = (m == 0) ? wq : ((m == 1) ? wk : wv);
    Wt = Wqkv + (size_t)m * 1024 * 1024;
    K = 1024; N = 1024; b2 = tb & 1023;
  } else if (tb < 4096)  { W = wo;  Wt = Wo;   K = 1024; N = 1024; b2 = tb - 3072; }
  else if (tb < 5632)    { W = f1;  Wt = Wf1;  K = 1024; N = 1536; b2 = tb - 4096; }
  else if (tb < 7168)    { W = f2;  Wt = Wf2;  K = 1536; N = 1024; b2 = tb - 5632; }
  else if (tb < 9216)    { W = sgf; Wt = Wsgf; K = 256;  N = 8192; b2 = tb - 7168; }
  else if (tb < 10240)   { W = swg; Wt = Wswg; K = 256;  N = 4096; b2 = tb - 9216; }
  else if (tb < 10752)   { W = sh1; Wt = Wsh1; K = 2048; N = 256;  b2 = tb - 10240; }
  else                   { W = scw; Wt = Wsc;  K = 1024; N = 32;   b2 = tb - 10752; }
  int ntx = N >> 5;
  int ty_ = b2 / ntx, tx_ = b2 - ty_ * ntx;
  int nb = tx_ * 32, kb = ty_ * 32;
  int tx = threadIdx.x & 31, ty = threadIdx.x >> 5;
#pragma unroll
  for (int i = 0; i < 4; ++i)
    tile[(ty + i * 8) * 33 + tx] = W[(size_t)(kb + ty + i * 8) * N + nb + tx];
  __syncthreads();
#pragma unroll
  for (int i = 0; i < 4; ++i)
    Wt[(size_t)(nb + ty + i * 8) * K + kb + tx] = __float2bfloat16(tile[tx * 33 + ty + i * 8]);
}

// ---------------- standalone transpose (layer-0 prologue) ------------------------------
__global__ __launch_bounds__(256) void transpose_layer(
    const float* wq, const float* wk, const float* wv, const float* wo,
    const float* f1, const float* f2, const float* sgf, const float* swg,
    const float* sh1, const float* scw,
    const float* bq, const float* bk, const float* bv,
    bf16* Wqkv, bf16* Wo, bf16* Wf1, bf16* Wf2, bf16* Wsgf, bf16* Wswg,
    bf16* Wsh1, bf16* Wsc, float* bqkv) {
  __shared__ float tile[32 * 33];
  transpose_body(blockIdx.x, tile, wq, wk, wv, wo, f1, f2, sgf, swg, sh1, scw,
                 bq, bk, bv, Wqkv, Wo, Wf1, Wf2, Wsgf, Wswg, Wsh1, Wsc, bqkv);
}

__global__ __launch_bounds__(256) void cvt_f32_bf16_k(const float* __restrict__ in,
                                                      bf16* __restrict__ out, long long n) {
  long long i = ((long long)blockIdx.x * 256 + threadIdx.x) * 4;
  if (i + 3 < n) {
    float4 v = *(const float4*)(in + i);
    out[i + 0] = __float2bfloat16(v.x);
    out[i + 1] = __float2bfloat16(v.y);
    out[i + 2] = __float2bfloat16(v.z);
    out[i + 3] = __float2bfloat16(v.w);
  }
}

// ---------------- megaA: QKV(1536, BK=64 single-buf) || c(128) || transpose(10796) -----
// R23 fix: B-read base was applied twice (rdB0 had +8192 AND the read added +8192) ->
// OOB LDS reads -> NaN. rdB0 is now region-relative; reads add the 8192 base once.
__global__ __launch_bounds__(256) void megaA(
    const bf16* __restrict__ xb,
    const bf16* __restrict__ Wqkv, const float* __restrict__ bqkv,
    bf16* __restrict__ qkvb,
    const bf16* __restrict__ Wsc, bf16* __restrict__ cbuf,
    int doT,
    const float* wq, const float* wk, const float* wv, const float* wo,
    const float* f1, const float* f2, const float* sgf, const float* swg,
    const float* sh1, const float* scw,
    const float* bq, const float* bk, const float* bv,
    bf16* WqkvN, bf16* WoN, bf16* Wf1N, bf16* Wf2N, bf16* WsgfN, bf16* WswgN,
    bf16* Wsh1N, bf16* WscN, float* bqkvN) {
  __shared__ __align__(128) short LB[16384];  // 32KB union
  const int bid = blockIdx.x;
  const int t = threadIdx.x;
  if (bid < 1536) {
    const int lane = t & 63, wave = t >> 6;
    int xcd = bid & 7, lid = bid >> 3;
    int swz = xcd * 192 + lid;
    int by = swz / 24, bx = swz - by * 24;
    int m0 = by << 7, n0 = bx << 7;
    int wr = wave >> 1, wc = wave & 1;
    int fr = lane & 15, fk = (lane >> 4) << 3;
    f32x4 acc[4][4] = {};
    int row0 = t >> 2, ko0 = (t & 3) << 3;
    const bf16* Ag0 = xb + (size_t)(m0 + row0) * 1024 + ko0;
    const bf16* Ag1 = xb + (size_t)(m0 + 64 + row0) * 1024 + ko0;
    const bf16* Bg0 = Wqkv + (size_t)(n0 + row0) * 1024 + ko0;
    const bf16* Bg1 = Wqkv + (size_t)(n0 + 64 + row0) * 1024 + ko0;
    const int rdA0 = (wr * 64 + fr) * 32 + fk;  // region-relative
    const int rdB0 = (wc * 64 + fr) * 32 + fk;  // region-relative (R23 fix)
    for (int kt = 0; kt < 16; ++kt) {
      int k0 = kt << 6;
#pragma unroll
      for (int s = 0; s < 2; ++s) {
        GLOAD_LDS16(Ag0 + k0 + s * 32, LB + s * 4096 + wave * 512);
        GLOAD_LDS16(Ag1 + k0 + s * 32, LB + s * 4096 + 2048 + wave * 512);
        GLOAD_LDS16(Bg0 + k0 + s * 32, LB + 8192 + s * 4096 + wave * 512);
        GLOAD_LDS16(Bg1 + k0 + s * 32, LB + 8192 + s * 4096 + 2048 + wave * 512);
      }
      __syncthreads();  // vmcnt(0) drain: full K-block resident
#pragma unroll
      for (int h = 0; h < 2; ++h) {
        bf16x8 af[4], bfv[4];
#pragma unroll
        for (int a = 0; a < 4; ++a)
          af[a] = *(const bf16x8*)(LB + h * 4096 + rdA0 + a * 512);
#pragma unroll
        for (int b = 0; b < 4; ++b)
          bfv[b] = *(const bf16x8*)(LB + 8192 + h * 4096 + rdB0 + b * 512);
#pragma unroll
        for (int a = 0; a < 4; ++a)
#pragma unroll
          for (int b = 0; b < 4; ++b) MFMA16(acc[a][b], af[a], bfv[b]);
      }
      __syncthreads();  // all reads done before next stage overwrites
    }
    int lr = (lane >> 4) << 2, lc = lane & 15;
#pragma unroll
    for (int a = 0; a < 4; ++a)
#pragma unroll
      for (int b = 0; b < 4; ++b) {
        int col = n0 + wc * 64 + b * 16 + lc;
        float bv = bqkv[col];
#pragma unroll
        for (int j = 0; j < 4; ++j) {
          int rowi = m0 + wr * 64 + a * 16 + lr + j;
          qkvb[(size_t)rowi * 3072 + col] = __float2bfloat16(acc[a][b][j] + bv);
        }
      }
  } else if (bid < 1664) {
    const int lane = t & 63, w = t >> 6;
    const int fr = lane & 15, s4 = lane >> 4;
    const int row0 = ((bid - 1536) * 4 + w) * 16;
    f32x4 acc[2] = {};
    const bf16* Arow = xb + (size_t)(row0 + fr) * 1024 + s4 * 8;
    const bf16* B0 = Wsc + (size_t)fr * 1024 + s4 * 8;
    const bf16* B1 = Wsc + (size_t)(16 + fr) * 1024 + s4 * 8;
#pragma unroll 8
    for (int kt = 0; kt < 32; ++kt) {
      bf16x8 a = *(const bf16x8*)(Arow + kt * 32);
      bf16x8 b0 = *(const bf16x8*)(B0 + kt * 32);
      bf16x8 b1 = *(const bf16x8*)(B1 + kt * 32);
      acc[0] = __builtin_amdgcn_mfma_f32_16x16x32_bf16(a, b0, acc[0], 0, 0, 0);
      acc[1] = __builtin_amdgcn_mfma_f32_16x16x32_bf16(a, b1, acc[1], 0, 0, 0);
    }
#pragma unroll
    for (int n2 = 0; n2 < 2; ++n2)
#pragma unroll
      for (int j = 0; j < 4; ++j)
        cbuf[(size_t)(row0 + s4 * 4 + j) * 32 + n2 * 16 + fr] =
            __float2bfloat16(acc[n2][j]);
  } else {
    if (!doT) return;
    transpose_body(bid - 1664, (float*)LB, wq, wk, wv, wo, f1, f2, sgf, swg, sh1, scw,
                   bq, bk, bv, WqkvN, WoN, Wf1N, Wf2N, WsgfN, WswgN, Wsh1N, WscN, bqkvN);
  }
}

// ---------------- 64x64 bf16 MFMA GEMM, BK=64, SINGLE-buffered (R21 proven) ------------
template <int ACT, bool OUTBF16, bool BIAS>
__global__ __launch_bounds__(256) void gemm64b(const bf16* __restrict__ A,
                                               const bf16* __restrict__ Bt,
                                               const float* __restrict__ bias,
                                               float* __restrict__ Cf, bf16* __restrict__ Cb,
                                               int M, int N, int K) {
  __shared__ __align__(128) short As[4096];  // [sub][64rows][32cols]
  __shared__ __align__(128) short Bs[4096];
  int t = threadIdx.x;
  int lane = t & 63, wave = t >> 6;
  // bijective XCD swizzle (m204)
  int nbx = N >> 6;
  int nwg = gridDim.x;
  int q = nwg >> 3, r = nwg & 7;
  int xcd = blockIdx.x & 7, lid = blockIdx.x >> 3;
  int swz = (xcd < r ? xcd * (q + 1) : r * (q + 1) + (xcd - r) * q) + lid;
  int by = swz / nbx, bx = swz - by * nbx;
  int m0 = by << 6, n0 = bx << 6;
  int fr = lane & 15;
  int fk = (lane >> 4) << 3;

  f32x4 acc[4] = {};  // AR=1, AC=4

  int row0 = t >> 2, ko0 = (t & 3) << 3;
  const bf16* Ag0 = A + (size_t)(m0 + row0) * K + ko0;
  const bf16* Bg0 = Bt + (size_t)(n0 + row0) * K + ko0;

  int nk = K >> 6;
  const int rdA = (wave * 16 + fr) * 32 + fk;  // 16 rows/wave
  const int rdB = fr * 32 + fk;

  for (int kt = 0; kt < nk; ++kt) {
    int k0 = kt << 6;
#pragma unroll
    for (int s = 0; s < 2; ++s) {
      GLOAD_LDS16(Ag0 + k0 + s * 32, As + s * 2048 + wave * 512);
      GLOAD_LDS16(Bg0 + k0 + s * 32, Bs + s * 2048 + wave * 512);
    }
    __syncthreads();  // vmcnt(0) drain: K-block resident
    bf16x8 af[2], bfv[4][2];
#pragma unroll
    for (int h = 0; h < 2; ++h) {
      af[h] = *(const bf16x8*)(As + h * 2048 + rdA);
#pragma unroll
      for (int b = 0; b < 4; ++b)
        bfv[b][h] = *(const bf16x8*)(Bs + h * 2048 + rdB + b * 512);
    }
#pragma unroll
    for (int h = 0; h < 2; ++h)
#pragma unroll
      for (int b = 0; b < 4; ++b) MFMA16(acc[b], af[h], bfv[b][h]);
    __syncthreads();  // all reads done before next stage overwrites
  }
  int lr = (lane >> 4) << 2;
  int lc = lane & 15;
#pragma unroll
  for (int b = 0; b < 4; ++b) {
    int col = n0 + b * 16 + lc;
    float bv = 0.0f;
    if constexpr (BIAS) bv = bias[col];
#pragma unroll
    for (int j = 0; j < 4; ++j) {
      int rowi = m0 + wave * 16 + lr + j;
      float v = acc[b][j] + bv;
      if constexpr (ACT == 1) v = silu_f(v);
      if constexpr (ACT == 2) v = mish_f(v);
      if constexpr (OUTBF16) Cb[(size_t)rowi * N + col] = __float2bfloat16(v);
      else Cf[(size_t)rowi * N + col] = v;
    }
  }
}

// ---------------- 1-wave 16x16-tile GEMM, direct-from-global ---------------------------
template <int ACT>
__global__ __launch_bounds__(64) void gemm_wave16(const bf16* __restrict__ A,
                                                  const bf16* __restrict__ Bt,
                                                  const float* __restrict__ bias,
                                                  float* __restrict__ Cf,
                                                  int N, int K) {
  const int lane = threadIdx.x;
  const int fr = lane & 15, s4 = lane >> 4;
  const int ncols = N >> 4;
  const int rb = blockIdx.x / ncols, cb = blockIdx.x - rb * ncols;
  const int row0 = rb << 4, col0 = cb << 4;
  f32x4 acc = {};
  const bf16* Arow = A + (size_t)(row0 + fr) * K + s4 * 8;
  const bf16* Brow = Bt + (size_t)(col0 + fr) * K + s4 * 8;
  const int nk = K >> 5;
#pragma unroll 8
  for (int kt = 0; kt < nk; ++kt) {
    bf16x8 a = *(const bf16x8*)(Arow + kt * 32);
    bf16x8 b = *(const bf16x8*)(Brow + kt * 32);
    acc = __builtin_amdgcn_mfma_f32_16x16x32_bf16(a, b, acc, 0, 0, 0);
  }
#pragma unroll
  for (int j = 0; j < 4; ++j) {
    int col = col0 + fr;
    float v = acc[j] + bias[col];
    if constexpr (ACT == 1) v = silu_f(v);
    Cf[(size_t)(row0 + s4 * 4 + j) * N + col] = v;
  }
}

// ---------------- LN over 256 cols ----------------------------------------------------
__global__ __launch_bounds__(256) void ln256_kernel(const float* __restrict__ hpre,
                                                    const float* __restrict__ gam,
                                                    const float* __restrict__ bet,
                                                    bf16* __restrict__ hb) {
  __shared__ float rsm[4], rs2[4], st2[2];
  int t = threadIdx.x, row = blockIdx.x;
  float sv = hpre[(size_t)row * 256 + t];
  float s = sv, s2 = sv * sv;
#pragma unroll
  for (int o = 32; o > 0; o >>= 1) { s += __shfl_down(s, o); s2 += __shfl_down(s2, o); }
  if ((t & 63) == 0) { rsm[t >> 6] = s; rs2[t >> 6] = s2; }
  __syncthreads();
  if (t == 0) {
    float a = rsm[0] + rsm[1] + rsm[2] + rsm[3];
    float b2 = rs2[0] + rs2[1] + rs2[2] + rs2[3];
    float m = a * (1.0f / 256.0f);
    st2[0] = m;
    st2[1] = rsqrtf(b2 * (1.0f / 256.0f) - m * m + LN_EPS);
  }
  __syncthreads();
  float y = (sv - st2[0]) * st2[1] * gam[t] + bet[t];
  hb[(size_t)row * 256 + t] = __float2bfloat16(y);
}

// ---------------- LN over 8192 cols ----------------------------------------------------
__global__ __launch_bounds__(1024) void ln8192_kernel(const float* __restrict__ gpre,
                                                      const float* __restrict__ gam,
                                                      const float* __restrict__ bet,
                                                      bf16* __restrict__ gb) {
  __shared__ float rsm[16], rs2[16], st2[2];
  int t = threadIdx.x, row = blockIdx.x;
  const float* p = gpre + (size_t)row * 8192;
  float v[8];
  float s = 0.0f, s2 = 0.0f;
#pragma unroll
  for (int i = 0; i < 8; ++i) {
    v[i] = p[t + i * 1024];
    s += v[i];
    s2 += v[i] * v[i];
  }
#pragma unroll
  for (int o = 32; o > 0; o >>= 1) { s += __shfl_down(s, o); s2 += __shfl_down(s2, o); }
  int lane = t & 63, w = t >> 6;
  if (lane == 0) { rsm[w] = s; rs2[w] = s2; }
  __syncthreads();
  if (t == 0) {
    float a = 0.0f, b2 = 0.0f;
#pragma unroll
    for (int i = 0; i < 16; ++i) { a += rsm[i]; b2 += rs2[i]; }
    float m = a * (1.0f / 8192.0f);
    st2[0] = m;
    st2[1] = rsqrtf(b2 * (1.0f / 8192.0f) - m * m + LN_EPS);
  }
  __syncthreads();
  float m = st2[0], r = st2[1];
#pragma unroll
  for (int i = 0; i < 8; ++i) {
    int n = t + i * 1024;
    gb[(size_t)row * 8192 + n] = __float2bfloat16((v[i] - m) * r * gam[n] + bet[n]);
  }
}

// ---------------- residual + LN over 1024 cols (f32 base, bf16 delta) ------------------
__global__ __launch_bounds__(256) void ln_residual_kernel(const float* __restrict__ base,
                                                          const bf16* __restrict__ delta,
                                                          const float* __restrict__ gam,
                                                          const float* __restrict__ bet,
                                                          float* __restrict__ outf,
                                                          bf16* __restrict__ outb) {
  __shared__ float rsm[4], rs2[4], st2[2];
  int t = threadIdx.x, row = blockIdx.x;
  float4 bv = ((const float4*)(base + (size_t)row * 1024))[t];
  ushort4 du = ((const ushort4*)(delta + (size_t)row * 1024))[t];
  float4 v;
  v.x = bv.x + bfu2f(du.x) * ALPHA_F;
  v.y = bv.y + bfu2f(du.y) * ALPHA_F;
  v.z = bv.z + bfu2f(du.z) * ALPHA_F;
  v.w = bv.w + bfu2f(du.w) * ALPHA_F;
  float s = v.x + v.y + v.z + v.w;
  float s2 = v.x * v.x + v.y * v.y + v.z * v.z + v.w * v.w;
#pragma unroll
  for (int o = 32; o > 0; o >>= 1) { s += __shfl_down(s, o); s2 += __shfl_down(s2, o); }
  if ((t & 63) == 0) { rsm[t >> 6] = s; rs2[t >> 6] = s2; }
  __syncthreads();
  if (t == 0) {
    float a = rsm[0] + rsm[1] + rsm[2] + rsm[3];
    float b2 = rs2[0] + rs2[1] + rs2[2] + rs2[3];
    float m = a * (1.0f / 1024.0f);
    st2[0] = m;
    st2[1] = rsqrtf(b2 * (1.0f / 1024.0f) - m * m + LN_EPS);
  }
  __syncthreads();
  float m = st2[0], r = st2[1];
  float4 g4 = ((const float4*)gam)[t];
  float4 b4 = ((const float4*)bet)[t];
  float4 y;
  y.x = (v.x - m) * r * g4.x + b4.x;
  y.y = (v.y - m) * r * g4.y + b4.y;
  y.z = (v.z - m) * r * g4.z + b4.z;
  y.w = (v.w - m) * r * g4.w + b4.w;
  ((float4*)(outf + (size_t)row * 1024))[t] = y;
  ushort4 o4;
  o4.x = f2bfu(y.x); o4.y = f2bfu(y.y); o4.z = f2bfu(y.z); o4.w = f2bfu(y.w);
  ((ushort4*)(outb + (size_t)row * 1024))[t] = o4;
}

// ---------------- MFMA fused attention per (b,h) ---------------------------------------
__global__ __launch_bounds__(256) void attn_kernel(const bf16* __restrict__ qkv,
                                                   const bf16* __restrict__ sw,
                                                   bf16* __restrict__ avb) {
  __shared__ __align__(16) short Vt[32 * 72];
  __shared__ __align__(16) short Pl[64 * 72];
  const int t = threadIdx.x, lane = t & 63, w = t >> 6;
  const int fr = lane & 15, s4 = lane >> 4;
  const int bh = blockIdx.x, b = bh >> 5, h = bh & 31;
  const size_t qb = (size_t)b * 64 * 3072 + h * 32;
  {
    int k = t >> 2, d0 = (t & 3) * 8;
    bf16x8 v = *(const bf16x8*)(qkv + qb + (size_t)k * 3072 + 2048 + d0);
#pragma unroll
    for (int i = 0; i < 8; ++i) Vt[(d0 + i) * 72 + k] = v[i];
  }
  f32x4 acc[4] = {};
  {
    bf16x8 aq = *(const bf16x8*)(qkv + qb + (size_t)(16 * w + fr) * 3072 + s4 * 8);
#pragma unroll
    for (int n = 0; n < 4; ++n) {
      bf16x8 bk = *(const bf16x8*)(qkv + qb + (size_t)(n * 16 + fr) * 3072 + 1024 + s4 * 8);
      acc[n] = __builtin_amdgcn_mfma_f32_16x16x32_bf16(aq, bk, acc[n], 0, 0, 0);
    }
  }
  const bf16* swp = sw + (size_t)bh * 4096;
  float rinv[4];
#pragma unroll
  for (int j = 0; j < 4; ++j) {
    int q = 16 * w + s4 * 4 + j;
    float pv[4];
    float mx = -1e30f;
#pragma unroll
    for (int n = 0; n < 4; ++n) {
      float v = acc[n][j] * 0.17677669529663687f +
                __bfloat162float(swp[q * 64 + n * 16 + fr]);
      pv[n] = v;
      mx = fmaxf(mx, v);
    }
    mx = fmaxf(mx, __shfl_xor(mx, 1));
    mx = fmaxf(mx, __shfl_xor(mx, 2));
    mx = fmaxf(mx, __shfl_xor(mx, 4));
    mx = fmaxf(mx, __shfl_xor(mx, 8));
    float sum = 0.0f;
#pragma unroll
    for (int n = 0; n < 4; ++n) {
      float e = __expf(pv[n] - mx);
      sum += e;
      ((bf16*)Pl)[q * 72 + n * 16 + fr] = __float2bfloat16(e);
    }
    sum += __shfl_xor(sum, 1);
    sum += __shfl_xor(sum, 2);
    sum += __shfl_xor(sum, 4);
    sum += __shfl_xor(sum, 8);
    rinv[j] = 1.0f / sum;
  }
  __syncthreads();
  f32x4 acc2[2] = {};
#pragma unroll
  for (int kt = 0; kt < 2; ++kt) {
    bf16x8 ap = *(const bf16x8*)(Pl + (16 * w + fr) * 72 + kt * 32 + s4 * 8);
#pragma unroll
    for (int n2 = 0; n2 < 2; ++n2) {
      bf16x8 bv = *(const bf16x8*)(Vt + (n2 * 16 + fr) * 72 + kt * 32 + s4 * 8);
      acc2[n2] = __builtin_amdgcn_mfma_f32_16x16x32_bf16(ap, bv, acc2[n2], 0, 0, 0);
    }
  }
#pragma unroll
  for (int n2 = 0; n2 < 2; ++n2) {
#pragma unroll
    for (int j = 0; j < 4; ++j) {
      int q = 16 * w + s4 * 4 + j;
      int d = n2 * 16 + fr;
      avb[(size_t)(b * 64 + q) * 1024 + h * 32 + d] =
          __float2bfloat16(acc2[n2][j] * rinv[j]);
    }
  }
}

extern "C" void kernel_launch(void* const* d_in, const int* in_sizes, int n_in,
                              void* d_out, int out_size, void* d_ws, size_t ws_size,
                              hipStream_t stream) {
  const float* x_in   = (const float*)d_in[0];
  const float* wq_w   = (const float*)d_in[1];
  const float* wq_b   = (const float*)d_in[2];
  const float* wk_w   = (const float*)d_in[3];
  const float* wk_b   = (const float*)d_in[4];
  const float* wv_w   = (const float*)d_in[5];
  const float* wv_b   = (const float*)d_in[6];
  const float* wo_w   = (const float*)d_in[7];
  const float* wo_b   = (const float*)d_in[8];
  const float* sc_w   = (const float*)d_in[9];
  const float* sh1_w  = (const float*)d_in[10];
  const float* sh1_b  = (const float*)d_in[11];
  const float* sln1_g = (const float*)d_in[12];
  const float* sln1_b = (const float*)d_in[13];
  const float* sgf_w  = (const float*)d_in[14];
  const float* sgf_b  = (const float*)d_in[15];
  const float* sln2_g = (const float*)d_in[16];
  const float* sln2_b = (const float*)d_in[17];
  const float* swg_w  = (const float*)d_in[18];
  const float* ffn1_w = (const float*)d_in[19];
  const float* ffn1_b = (const float*)d_in[20];
  const float* ffn2_w = (const float*)d_in[21];
  const float* ffn2_b = (const float*)d_in[22];
  const float* n1_g   = (const float*)d_in[23];
  const float* n1_b   = (const float*)d_in[24];
  const float* n2_g   = (const float*)d_in[25];
  const float* n2_b   = (const float*)d_in[26];

  char* ws = (char*)d_ws;
  size_t off = 0;
  auto alloc = [&](size_t bytes) -> void* {
    void* p = ws + off;
    off += (bytes + 255) & ~(size_t)255;
    return p;
  };
  bf16*  xb    = (bf16*)alloc(8192ULL * 1024 * 2);
  float* P0    = (float*)alloc(8192ULL * 1024 * 4);
  float* P1    = (float*)alloc(8192ULL * 1024 * 4);
  bf16*  dT    = (bf16*)alloc(8192ULL * 1024 * 2);
  // double-buffered transposed weights (buf = layer & 1)
  bf16*  WqkvB = (bf16*)alloc(2ULL * 3072 * 1024 * 2);
  float* bqkvB = (float*)alloc(2ULL * 3072 * 4);
  bf16*  WoB   = (bf16*)alloc(2ULL * 1024 * 1024 * 2);
  bf16*  Wf1B  = (bf16*)alloc(2ULL * 1536 * 1024 * 2);
  bf16*  Wf2B  = (bf16*)alloc(2ULL * 1024 * 1536 * 2);
  bf16*  WsgfB = (bf16*)alloc(2ULL * 8192 * 256 * 2);
  bf16*  WswgB = (bf16*)alloc(2ULL * 4096 * 256 * 2);
  bf16*  Wsh1B = (bf16*)alloc(2ULL * 256 * 2048 * 2);
  bf16*  WscB  = (bf16*)alloc(2ULL * 32 * 1024 * 2);
  bf16*  qkvb  = (bf16*)alloc(8192ULL * 3072 * 2);
  bf16*  cbuf  = (bf16*)alloc(8192ULL * 32 * 2);
  float* hpre  = (float*)alloc(128ULL * 256 * 4);
  bf16*  hbb   = (bf16*)alloc(128ULL * 256 * 2);
  float* gpre  = (float*)alloc(128ULL * 8192 * 4);
  bf16*  gbb   = (bf16*)alloc(128ULL * 8192 * 2);
  bf16*  swb   = (bf16*)alloc(4096ULL * 4096 * 2);
  bf16*  avb   = (bf16*)alloc(8192ULL * 1024 * 2);
  bf16*  out1b = (bf16*)alloc(8192ULL * 1024 * 2);
  bf16*  f1b   = (bf16*)alloc(8192ULL * 1536 * 2);
  if (off > ws_size) {
    sentinel_k<<<1, 1, 0, stream>>>((float*)d_out);
    return;
  }

  cvt_f32_bf16_k<<<8192, 256, 0, stream>>>(x_in, xb, 8192LL * 1024);
  // prologue: transpose layer 0 into buf 0
  transpose_layer<<<10796, 256, 0, stream>>>(
      wq_w, wk_w, wv_w, wo_w, ffn1_w, ffn2_w, sgf_w, swg_w, sh1_w, sc_w,
      wq_b, wk_b, wv_b,
      WqkvB, WoB, Wf1B, Wf2B, WsgfB, WswgB, Wsh1B, WscB, bqkvB);

  for (int l = 0; l < 15; ++l) {
    const int cur = l & 1, nxt = cur ^ 1;
    const int lp = l + 1;
    bf16*  Wqkv = WqkvB + (size_t)cur * 3072 * 1024;
    float* bqkv = bqkvB + (size_t)cur * 3072;
    bf16*  Wo   = WoB   + (size_t)cur * 1024 * 1024;
    bf16*  Wf1  = Wf1B  + (size_t)cur * 1536 * 1024;
    bf16*  Wf2  = Wf2B  + (size_t)cur * 1024 * 1536;
    bf16*  Wsgf = WsgfB + (size_t)cur * 8192 * 256;
    bf16*  Wswg = WswgB + (size_t)cur * 4096 * 256;
    bf16*  Wsh1 = Wsh1B + (size_t)cur * 256 * 2048;
    bf16*  Wsc  = WscB  + (size_t)cur * 32 * 1024;

    const float* xc = (l == 0) ? x_in : ((l & 1) ? P0 : P1);
    float* Pout = (l & 1) ? P1 : P0;

    // megaA: QKV(BK=64) || c || transpose(l+1)
    megaA<<<12460, 256, 0, stream>>>(
        xb, Wqkv, bqkv, qkvb, Wsc, cbuf, (l < 14) ? 1 : 0,
        wq_w + (size_t)lp * 1048576, wk_w + (size_t)lp * 1048576,
        wv_w + (size_t)lp * 1048576, wo_w + (size_t)lp * 1048576,
        ffn1_w + (size_t)lp * 1024 * 1536, ffn2_w + (size_t)lp * 1536 * 1024,
        sgf_w + (size_t)lp * 256 * 8192, swg_w + (size_t)lp * 256 * 4096,
        sh1_w + (size_t)lp * 2048 * 256, sc_w + (size_t)lp * 1024 * 32,
        wq_b + (size_t)lp * 1024, wk_b + (size_t)lp * 1024, wv_b + (size_t)lp * 1024,
        WqkvB + (size_t)nxt * 3072 * 1024, WoB + (size_t)nxt * 1024 * 1024,
        Wf1B + (size_t)nxt * 1536 * 1024, Wf2B + (size_t)nxt * 1024 * 1536,
        WsgfB + (size_t)nxt * 8192 * 256, WswgB + (size_t)nxt * 4096 * 256,
        Wsh1B + (size_t)nxt * 256 * 2048, WscB + (size_t)nxt * 32 * 1024,
        bqkvB + (size_t)nxt * 3072);
    // smolgen chain (MFMA wave16 path)
    gemm_wave16<1><<<128, 64, 0, stream>>>(cbuf, Wsh1, sh1_b + l * 256, hpre, 256, 2048);
    ln256_kernel<<<128, 256, 0, stream>>>(hpre, sln1_g + l * 256, sln1_b + l * 256, hbb);
    gemm_wave16<1><<<4096, 64, 0, stream>>>(hbb, Wsgf, sgf_b + (size_t)l * 8192, gpre,
                                            8192, 256);
    ln8192_kernel<<<128, 1024, 0, stream>>>(gpre, sln2_g + (size_t)l * 8192,
                                            sln2_b + (size_t)l * 8192, gbb);
    // sw gemm (BK=64 single-buffered)
    gemm64b<0, true, false><<<4096, 256, 0, stream>>>(gbb, Wswg, nullptr, nullptr,
                                                      swb, 4096, 4096, 256);
    // attention
    attn_kernel<<<4096, 256, 0, stream>>>(qkvb, swb, avb);
    // output projection + LN1
    gemm64b<0, true, true><<<2048, 256, 0, stream>>>(avb, Wo, wo_b + l * 1024,
                                                     nullptr, dT, 8192, 1024, 1024);
    ln_residual_kernel<<<8192, 256, 0, stream>>>(xc, dT, n1_g + l * 1024, n1_b + l * 1024,
                                                 Pout, out1b);
    // FFN + LN2
    gemm64b<2, true, true><<<3072, 256, 0, stream>>>(out1b, Wf1, ffn1_b + l * 1536,
                                                     nullptr, f1b, 8192, 1536, 1024);
    gemm64b<0, true, true><<<2048, 256, 0, stream>>>(f1b, Wf2, ffn2_b + l * 1024,
                                                     nullptr, dT, 8192, 1024, 1536);
    float* xnext = (l == 14) ? (float*)d_out : Pout;
    ln_residual_kernel<<<8192, 256, 0, stream>>>(Pout, dT, n2_g + l * 1024, n2_b + l * 1024,
                                                 xnext, xb);
  }
}

// Round 25
// 5067.570 us; speedup vs baseline: 1.0232x; 1.0206x over previous
//
#include <hip/hip_runtime.h>
#include <hip/hip_bf16.h>

typedef __attribute__((ext_vector_type(8))) short bf16x8;
typedef __attribute__((ext_vector_type(4))) float f32x4;
typedef __hip_bfloat16 bf16;

#define ALPHA_F 0.42728713f
#define LN_EPS 1e-3f

__device__ __forceinline__ float silu_f(float x) { return x / (1.0f + __expf(-x)); }
__device__ __forceinline__ float mish_f(float x) {
  if (x > 20.0f) return x;
  float t = 1.0f + __expf(x);
  float t2 = t * t;
  return x * (t2 - 1.0f) / (t2 + 1.0f);
}
__device__ __forceinline__ unsigned short f2bfu(float x) {
  bf16 h = __float2bfloat16(x);
  return *(unsigned short*)&h;
}
__device__ __forceinline__ float bfu2f(unsigned short u) {
  unsigned int v = (unsigned int)u << 16;
  return *(float*)&v;
}

#define MFMA16(acc, a, b) \
  (acc) = __builtin_amdgcn_mfma_f32_16x16x32_bf16((a), (b), (acc), 0, 0, 0)

#define GLOAD_LDS16(gp, lp)                                                              \
  __builtin_amdgcn_global_load_lds((__attribute__((address_space(1))) void*)(void*)(gp), \
                                   (__attribute__((address_space(3))) void*)(void*)(lp), \
                                   16, 0, 0)

__global__ __launch_bounds__(1) void sentinel_k(float* __restrict__ o) { o[0] = 1.2345e7f; }

// ---------------- weight transpose body: W[K,N] f32 -> Wt[N,K] bf16 (+bias pack) -------
__device__ __forceinline__ void transpose_body(
    int tb, float* tile /* 32x33 LDS */,
    const float* wq, const float* wk, const float* wv, const float* wo,
    const float* f1, const float* f2, const float* sgf, const float* swg,
    const float* sh1, const float* scw,
    const float* bq, const float* bk, const float* bv,
    bf16* Wqkv, bf16* Wo, bf16* Wf1, bf16* Wf2, bf16* Wsgf, bf16* Wswg,
    bf16* Wsh1, bf16* Wsc, float* bqkv) {
  if (tb >= 10784) {  // bias pack
    int i = (tb - 10784) * 256 + threadIdx.x;
    if (i < 1024) bqkv[i] = bq[i];
    else if (i < 2048) bqkv[i] = bk[i - 1024];
    else bqkv[i] = bv[i - 2048];
    return;
  }
  const float* W;
  bf16* Wt;
  int K, N, b2;
  if (tb < 3072) {
    int m = tb >> 10;
    W = (m == 0) ? wq : ((m == 1) ? wk : wv);
    Wt = Wqkv + (size_t)m * 1024 * 1024;
    K = 1024; N = 1024; b2 = tb & 1023;
  } else if (tb < 4096)  { W = wo;  Wt = Wo;   K = 1024; N = 1024; b2 = tb - 3072; }
  else if (tb < 5632)    { W = f1;  Wt = Wf1;  K = 1024; N = 1536; b2 = tb - 4096; }
  else if (tb < 7168)    { W = f2;  Wt = Wf2;  K = 1536; N = 1024; b2 = tb - 5632; }
  else if (tb < 9216)    { W = sgf; Wt = Wsgf; K = 256;  N = 8192; b2 = tb - 7168; }
  else if (tb < 10240)   { W = swg; Wt = Wswg; K = 256;  N = 4096; b2 = tb - 9216; }
  else if (tb < 10752)   { W = sh1; Wt = Wsh1; K = 2048; N = 256;  b2 = tb - 10240; }
  else                   { W = scw; Wt = Wsc;  K = 1024; N = 32;   b2 = tb - 10752; }
  int ntx = N >> 5;
  int ty_ = b2 / ntx, tx_ = b2 - ty_ * ntx;
  int nb = tx_ * 32, kb = ty_ * 32;
  int tx = threadIdx.x & 31, ty = threadIdx.x >> 5;
#pragma unroll
  for (int i = 0; i < 4; ++i)
    tile[(ty + i * 8) * 33 + tx] = W[(size_t)(kb + ty + i * 8) * N + nb + tx];
  __syncthreads();
#pragma unroll
  for (int i = 0; i < 4; ++i)
    Wt[(size_t)(nb + ty + i * 8) * K + kb + tx] = __float2bfloat16(tile[tx * 33 + ty + i * 8]);
}

// ---------------- standalone transpose (layer-0 prologue) ------------------------------
__global__ __launch_bounds__(256) void transpose_layer(
    const float* wq, const float* wk, const float* wv, const float* wo,
    const float* f1, const float* f2, const float* sgf, const float* swg,
    const float* sh1, const float* scw,
    const float* bq, const float* bk, const float* bv,
    bf16* Wqkv, bf16* Wo, bf16* Wf1, bf16* Wf2, bf16* Wsgf, bf16* Wswg,
    bf16* Wsh1, bf16* Wsc, float* bqkv) {
  __shared__ float tile[32 * 33];
  transpose_body(blockIdx.x, tile, wq, wk, wv, wo, f1, f2, sgf, swg, sh1, scw,
                 bq, bk, bv, Wqkv, Wo, Wf1, Wf2, Wsgf, Wswg, Wsh1, Wsc, bqkv);
}

__global__ __launch_bounds__(256) void cvt_f32_bf16_k(const float* __restrict__ in,
                                                      bf16* __restrict__ out, long long n) {
  long long i = ((long long)blockIdx.x * 256 + threadIdx.x) * 4;
  if (i + 3 < n) {
    float4 v = *(const float4*)(in + i);
    out[i + 0] = __float2bfloat16(v.x);
    out[i + 1] = __float2bfloat16(v.y);
    out[i + 2] = __float2bfloat16(v.z);
    out[i + 3] = __float2bfloat16(v.w);
  }
}

// ---------------- megaA: QKV(1536, BK=32 16KB — R21 optimum) || c || transpose ---------
// R24: BK=64 QKV regressed (102->114us; occupancy 31->21%, FETCH 87->114MB — lost
// co-residency with transpose blocks). BK=32/16KB is the measured optimum.
__global__ __launch_bounds__(256) void megaA(
    const bf16* __restrict__ xb,
    const bf16* __restrict__ Wqkv, const float* __restrict__ bqkv,
    bf16* __restrict__ qkvb,
    const bf16* __restrict__ Wsc, bf16* __restrict__ cbuf,
    int doT,
    const float* wq, const float* wk, const float* wv, const float* wo,
    const float* f1, const float* f2, const float* sgf, const float* swg,
    const float* sh1, const float* scw,
    const float* bq, const float* bk, const float* bv,
    bf16* WqkvN, bf16* WoN, bf16* Wf1N, bf16* Wf2N, bf16* WsgfN, bf16* WswgN,
    bf16* Wsh1N, bf16* WscN, float* bqkvN) {
  __shared__ __align__(128) short LB[8192];  // 16KB union
  const int bid = blockIdx.x;
  const int t = threadIdx.x;
  if (bid < 1536) {
    const int lane = t & 63, wave = t >> 6;
    int xcd = bid & 7, lid = bid >> 3;
    int swz = xcd * 192 + lid;
    int by = swz / 24, bx = swz - by * 24;
    int m0 = by << 7, n0 = bx << 7;
    int wr = wave >> 1, wc = wave & 1;
    int fr = lane & 15, fk = (lane >> 4) << 3;
    f32x4 acc[4][4] = {};
    int row0 = t >> 2, ko0 = (t & 3) << 3;
    const bf16* Ag0 = xb + (size_t)(m0 + row0) * 1024 + ko0;
    const bf16* Ag1 = xb + (size_t)(m0 + 64 + row0) * 1024 + ko0;
    const bf16* Bg0 = Wqkv + (size_t)(n0 + row0) * 1024 + ko0;
    const bf16* Bg1 = Wqkv + (size_t)(n0 + 64 + row0) * 1024 + ko0;
    const int rdA = (wr * 64 + fr) * 32 + fk;
    const int rdB = 4096 + (wc * 64 + fr) * 32 + fk;
    for (int kt = 0; kt < 32; ++kt) {
      int k0 = kt << 5;
      GLOAD_LDS16(Ag0 + k0, LB + wave * 512);
      GLOAD_LDS16(Ag1 + k0, LB + 2048 + wave * 512);
      GLOAD_LDS16(Bg0 + k0, LB + 4096 + wave * 512);
      GLOAD_LDS16(Bg1 + k0, LB + 6144 + wave * 512);
      __syncthreads();
      bf16x8 af[4], bfv[4];
#pragma unroll
      for (int a = 0; a < 4; ++a) af[a] = *(const bf16x8*)(LB + rdA + a * 512);
#pragma unroll
      for (int b = 0; b < 4; ++b) bfv[b] = *(const bf16x8*)(LB + rdB + b * 512);
#pragma unroll
      for (int a = 0; a < 4; ++a)
#pragma unroll
        for (int b = 0; b < 4; ++b) MFMA16(acc[a][b], af[a], bfv[b]);
      __syncthreads();
    }
    int lr = (lane >> 4) << 2, lc = lane & 15;
#pragma unroll
    for (int a = 0; a < 4; ++a)
#pragma unroll
      for (int b = 0; b < 4; ++b) {
        int col = n0 + wc * 64 + b * 16 + lc;
        float bv = bqkv[col];
#pragma unroll
        for (int j = 0; j < 4; ++j) {
          int rowi = m0 + wr * 64 + a * 16 + lr + j;
          qkvb[(size_t)rowi * 3072 + col] = __float2bfloat16(acc[a][b][j] + bv);
        }
      }
  } else if (bid < 1664) {
    const int lane = t & 63, w = t >> 6;
    const int fr = lane & 15, s4 = lane >> 4;
    const int row0 = ((bid - 1536) * 4 + w) * 16;
    f32x4 acc[2] = {};
    const bf16* Arow = xb + (size_t)(row0 + fr) * 1024 + s4 * 8;
    const bf16* B0 = Wsc + (size_t)fr * 1024 + s4 * 8;
    const bf16* B1 = Wsc + (size_t)(16 + fr) * 1024 + s4 * 8;
#pragma unroll 8
    for (int kt = 0; kt < 32; ++kt) {
      bf16x8 a = *(const bf16x8*)(Arow + kt * 32);
      bf16x8 b0 = *(const bf16x8*)(B0 + kt * 32);
      bf16x8 b1 = *(const bf16x8*)(B1 + kt * 32);
      acc[0] = __builtin_amdgcn_mfma_f32_16x16x32_bf16(a, b0, acc[0], 0, 0, 0);
      acc[1] = __builtin_amdgcn_mfma_f32_16x16x32_bf16(a, b1, acc[1], 0, 0, 0);
    }
#pragma unroll
    for (int n2 = 0; n2 < 2; ++n2)
#pragma unroll
      for (int j = 0; j < 4; ++j)
        cbuf[(size_t)(row0 + s4 * 4 + j) * 32 + n2 * 16 + fr] =
            __float2bfloat16(acc[n2][j]);
  } else {
    if (!doT) return;
    transpose_body(bid - 1664, (float*)LB, wq, wk, wv, wo, f1, f2, sgf, swg, sh1, scw,
                   bq, bk, bv, WqkvN, WoN, Wf1N, Wf2N, WsgfN, WswgN, Wsh1N, WscN, bqkvN);
  }
}

// ---------------- 64x64 bf16 MFMA GEMM, BK=64, SINGLE-buffered (R21 proven) ------------
template <int ACT, bool OUTBF16, bool BIAS>
__global__ __launch_bounds__(256) void gemm64b(const bf16* __restrict__ A,
                                               const bf16* __restrict__ Bt,
                                               const float* __restrict__ bias,
                                               float* __restrict__ Cf, bf16* __restrict__ Cb,
                                               int M, int N, int K) {
  __shared__ __align__(128) short As[4096];  // [sub][64rows][32cols]
  __shared__ __align__(128) short Bs[4096];
  int t = threadIdx.x;
  int lane = t & 63, wave = t >> 6;
  // bijective XCD swizzle (m204)
  int nbx = N >> 6;
  int nwg = gridDim.x;
  int q = nwg >> 3, r = nwg & 7;
  int xcd = blockIdx.x & 7, lid = blockIdx.x >> 3;
  int swz = (xcd < r ? xcd * (q + 1) : r * (q + 1) + (xcd - r) * q) + lid;
  int by = swz / nbx, bx = swz - by * nbx;
  int m0 = by << 6, n0 = bx << 6;
  int fr = lane & 15;
  int fk = (lane >> 4) << 3;

  f32x4 acc[4] = {};  // AR=1, AC=4

  int row0 = t >> 2, ko0 = (t & 3) << 3;
  const bf16* Ag0 = A + (size_t)(m0 + row0) * K + ko0;
  const bf16* Bg0 = Bt + (size_t)(n0 + row0) * K + ko0;

  int nk = K >> 6;
  const int rdA = (wave * 16 + fr) * 32 + fk;  // 16 rows/wave
  const int rdB = fr * 32 + fk;

  for (int kt = 0; kt < nk; ++kt) {
    int k0 = kt << 6;
#pragma unroll
    for (int s = 0; s < 2; ++s) {
      GLOAD_LDS16(Ag0 + k0 + s * 32, As + s * 2048 + wave * 512);
      GLOAD_LDS16(Bg0 + k0 + s * 32, Bs + s * 2048 + wave * 512);
    }
    __syncthreads();  // vmcnt(0) drain: K-block resident
    bf16x8 af[2], bfv[4][2];
#pragma unroll
    for (int h = 0; h < 2; ++h) {
      af[h] = *(const bf16x8*)(As + h * 2048 + rdA);
#pragma unroll
      for (int b = 0; b < 4; ++b)
        bfv[b][h] = *(const bf16x8*)(Bs + h * 2048 + rdB + b * 512);
    }
#pragma unroll
    for (int h = 0; h < 2; ++h)
#pragma unroll
      for (int b = 0; b < 4; ++b) MFMA16(acc[b], af[h], bfv[b][h]);
    __syncthreads();  // all reads done before next stage overwrites
  }
  int lr = (lane >> 4) << 2;
  int lc = lane & 15;
#pragma unroll
  for (int b = 0; b < 4; ++b) {
    int col = n0 + b * 16 + lc;
    float bv = 0.0f;
    if constexpr (BIAS) bv = bias[col];
#pragma unroll
    for (int j = 0; j < 4; ++j) {
      int rowi = m0 + wave * 16 + lr + j;
      float v = acc[b][j] + bv;
      if constexpr (ACT == 1) v = silu_f(v);
      if constexpr (ACT == 2) v = mish_f(v);
      if constexpr (OUTBF16) Cb[(size_t)rowi * N + col] = __float2bfloat16(v);
      else Cf[(size_t)rowi * N + col] = v;
    }
  }
}

// ---------------- 1-wave 16x16-tile GEMM, direct-from-global ---------------------------
template <int ACT>
__global__ __launch_bounds__(64) void gemm_wave16(const bf16* __restrict__ A,
                                                  const bf16* __restrict__ Bt,
                                                  const float* __restrict__ bias,
                                                  float* __restrict__ Cf,
                                                  int N, int K) {
  const int lane = threadIdx.x;
  const int fr = lane & 15, s4 = lane >> 4;
  const int ncols = N >> 4;
  const int rb = blockIdx.x / ncols, cb = blockIdx.x - rb * ncols;
  const int row0 = rb << 4, col0 = cb << 4;
  f32x4 acc = {};
  const bf16* Arow = A + (size_t)(row0 + fr) * K + s4 * 8;
  const bf16* Brow = Bt + (size_t)(col0 + fr) * K + s4 * 8;
  const int nk = K >> 5;
#pragma unroll 8
  for (int kt = 0; kt < nk; ++kt) {
    bf16x8 a = *(const bf16x8*)(Arow + kt * 32);
    bf16x8 b = *(const bf16x8*)(Brow + kt * 32);
    acc = __builtin_amdgcn_mfma_f32_16x16x32_bf16(a, b, acc, 0, 0, 0);
  }
#pragma unroll
  for (int j = 0; j < 4; ++j) {
    int col = col0 + fr;
    float v = acc[j] + bias[col];
    if constexpr (ACT == 1) v = silu_f(v);
    Cf[(size_t)(row0 + s4 * 4 + j) * N + col] = v;
  }
}

// ---------------- LN over 256 cols ----------------------------------------------------
__global__ __launch_bounds__(256) void ln256_kernel(const float* __restrict__ hpre,
                                                    const float* __restrict__ gam,
                                                    const float* __restrict__ bet,
                                                    bf16* __restrict__ hb) {
  __shared__ float rsm[4], rs2[4], st2[2];
  int t = threadIdx.x, row = blockIdx.x;
  float sv = hpre[(size_t)row * 256 + t];
  float s = sv, s2 = sv * sv;
#pragma unroll
  for (int o = 32; o > 0; o >>= 1) { s += __shfl_down(s, o); s2 += __shfl_down(s2, o); }
  if ((t & 63) == 0) { rsm[t >> 6] = s; rs2[t >> 6] = s2; }
  __syncthreads();
  if (t == 0) {
    float a = rsm[0] + rsm[1] + rsm[2] + rsm[3];
    float b2 = rs2[0] + rs2[1] + rs2[2] + rs2[3];
    float m = a * (1.0f / 256.0f);
    st2[0] = m;
    st2[1] = rsqrtf(b2 * (1.0f / 256.0f) - m * m + LN_EPS);
  }
  __syncthreads();
  float y = (sv - st2[0]) * st2[1] * gam[t] + bet[t];
  hb[(size_t)row * 256 + t] = __float2bfloat16(y);
}

// ---------------- LN over 8192 cols ----------------------------------------------------
__global__ __launch_bounds__(1024) void ln8192_kernel(const float* __restrict__ gpre,
                                                      const float* __restrict__ gam,
                                                      const float* __restrict__ bet,
                                                      bf16* __restrict__ gb) {
  __shared__ float rsm[16], rs2[16], st2[2];
  int t = threadIdx.x, row = blockIdx.x;
  const float* p = gpre + (size_t)row * 8192;
  float v[8];
  float s = 0.0f, s2 = 0.0f;
#pragma unroll
  for (int i = 0; i < 8; ++i) {
    v[i] = p[t + i * 1024];
    s += v[i];
    s2 += v[i] * v[i];
  }
#pragma unroll
  for (int o = 32; o > 0; o >>= 1) { s += __shfl_down(s, o); s2 += __shfl_down(s2, o); }
  int lane = t & 63, w = t >> 6;
  if (lane == 0) { rsm[w] = s; rs2[w] = s2; }
  __syncthreads();
  if (t == 0) {
    float a = 0.0f, b2 = 0.0f;
#pragma unroll
    for (int i = 0; i < 16; ++i) { a += rsm[i]; b2 += rs2[i]; }
    float m = a * (1.0f / 8192.0f);
    st2[0] = m;
    st2[1] = rsqrtf(b2 * (1.0f / 8192.0f) - m * m + LN_EPS);
  }
  __syncthreads();
  float m = st2[0], r = st2[1];
#pragma unroll
  for (int i = 0; i < 8; ++i) {
    int n = t + i * 1024;
    gb[(size_t)row * 8192 + n] = __float2bfloat16((v[i] - m) * r * gam[n] + bet[n]);
  }
}

// ---------------- residual + LN over 1024 cols (f32 base, bf16 delta) ------------------
__global__ __launch_bounds__(256) void ln_residual_kernel(const float* __restrict__ base,
                                                          const bf16* __restrict__ delta,
                                                          const float* __restrict__ gam,
                                                          const float* __restrict__ bet,
                                                          float* __restrict__ outf,
                                                          bf16* __restrict__ outb) {
  __shared__ float rsm[4], rs2[4], st2[2];
  int t = threadIdx.x, row = blockIdx.x;
  float4 bv = ((const float4*)(base + (size_t)row * 1024))[t];
  ushort4 du = ((const ushort4*)(delta + (size_t)row * 1024))[t];
  float4 v;
  v.x = bv.x + bfu2f(du.x) * ALPHA_F;
  v.y = bv.y + bfu2f(du.y) * ALPHA_F;
  v.z = bv.z + bfu2f(du.z) * ALPHA_F;
  v.w = bv.w + bfu2f(du.w) * ALPHA_F;
  float s = v.x + v.y + v.z + v.w;
  float s2 = v.x * v.x + v.y * v.y + v.z * v.z + v.w * v.w;
#pragma unroll
  for (int o = 32; o > 0; o >>= 1) { s += __shfl_down(s, o); s2 += __shfl_down(s2, o); }
  if ((t & 63) == 0) { rsm[t >> 6] = s; rs2[t >> 6] = s2; }
  __syncthreads();
  if (t == 0) {
    float a = rsm[0] + rsm[1] + rsm[2] + rsm[3];
    float b2 = rs2[0] + rs2[1] + rs2[2] + rs2[3];
    float m = a * (1.0f / 1024.0f);
    st2[0] = m;
    st2[1] = rsqrtf(b2 * (1.0f / 1024.0f) - m * m + LN_EPS);
  }
  __syncthreads();
  float m = st2[0], r = st2[1];
  float4 g4 = ((const float4*)gam)[t];
  float4 b4 = ((const float4*)bet)[t];
  float4 y;
  y.x = (v.x - m) * r * g4.x + b4.x;
  y.y = (v.y - m) * r * g4.y + b4.y;
  y.z = (v.z - m) * r * g4.z + b4.z;
  y.w = (v.w - m) * r * g4.w + b4.w;
  ((float4*)(outf + (size_t)row * 1024))[t] = y;
  ushort4 o4;
  o4.x = f2bfu(y.x); o4.y = f2bfu(y.y); o4.z = f2bfu(y.z); o4.w = f2bfu(y.w);
  ((ushort4*)(outb + (size_t)row * 1024))[t] = o4;
}

// ---------------- MFMA fused attention per (b,h) ---------------------------------------
__global__ __launch_bounds__(256) void attn_kernel(const bf16* __restrict__ qkv,
                                                   const bf16* __restrict__ sw,
                                                   bf16* __restrict__ avb) {
  __shared__ __align__(16) short Vt[32 * 72];
  __shared__ __align__(16) short Pl[64 * 72];
  const int t = threadIdx.x, lane = t & 63, w = t >> 6;
  const int fr = lane & 15, s4 = lane >> 4;
  const int bh = blockIdx.x, b = bh >> 5, h = bh & 31;
  const size_t qb = (size_t)b * 64 * 3072 + h * 32;
  {
    int k = t >> 2, d0 = (t & 3) * 8;
    bf16x8 v = *(const bf16x8*)(qkv + qb + (size_t)k * 3072 + 2048 + d0);
#pragma unroll
    for (int i = 0; i < 8; ++i) Vt[(d0 + i) * 72 + k] = v[i];
  }
  f32x4 acc[4] = {};
  {
    bf16x8 aq = *(const bf16x8*)(qkv + qb + (size_t)(16 * w + fr) * 3072 + s4 * 8);
#pragma unroll
    for (int n = 0; n < 4; ++n) {
      bf16x8 bk = *(const bf16x8*)(qkv + qb + (size_t)(n * 16 + fr) * 3072 + 1024 + s4 * 8);
      acc[n] = __builtin_amdgcn_mfma_f32_16x16x32_bf16(aq, bk, acc[n], 0, 0, 0);
    }
  }
  const bf16* swp = sw + (size_t)bh * 4096;
  float rinv[4];
#pragma unroll
  for (int j = 0; j < 4; ++j) {
    int q = 16 * w + s4 * 4 + j;
    float pv[4];
    float mx = -1e30f;
#pragma unroll
    for (int n = 0; n < 4; ++n) {
      float v = acc[n][j] * 0.17677669529663687f +
                __bfloat162float(swp[q * 64 + n * 16 + fr]);
      pv[n] = v;
      mx = fmaxf(mx, v);
    }
    mx = fmaxf(mx, __shfl_xor(mx, 1));
    mx = fmaxf(mx, __shfl_xor(mx, 2));
    mx = fmaxf(mx, __shfl_xor(mx, 4));
    mx = fmaxf(mx, __shfl_xor(mx, 8));
    float sum = 0.0f;
#pragma unroll
    for (int n = 0; n < 4; ++n) {
      float e = __expf(pv[n] - mx);
      sum += e;
      ((bf16*)Pl)[q * 72 + n * 16 + fr] = __float2bfloat16(e);
    }
    sum += __shfl_xor(sum, 1);
    sum += __shfl_xor(sum, 2);
    sum += __shfl_xor(sum, 4);
    sum += __shfl_xor(sum, 8);
    rinv[j] = 1.0f / sum;
  }
  __syncthreads();
  f32x4 acc2[2] = {};
#pragma unroll
  for (int kt = 0; kt < 2; ++kt) {
    bf16x8 ap = *(const bf16x8*)(Pl + (16 * w + fr) * 72 + kt * 32 + s4 * 8);
#pragma unroll
    for (int n2 = 0; n2 < 2; ++n2) {
      bf16x8 bv = *(const bf16x8*)(Vt + (n2 * 16 + fr) * 72 + kt * 32 + s4 * 8);
      acc2[n2] = __builtin_amdgcn_mfma_f32_16x16x32_bf16(ap, bv, acc2[n2], 0, 0, 0);
    }
  }
#pragma unroll
  for (int n2 = 0; n2 < 2; ++n2) {
#pragma unroll
    for (int j = 0; j < 4; ++j) {
      int q = 16 * w + s4 * 4 + j;
      int d = n2 * 16 + fr;
      avb[(size_t)(b * 64 + q) * 1024 + h * 32 + d] =
          __float2bfloat16(acc2[n2][j] * rinv[j]);
    }
  }
}

extern "C" void kernel_launch(void* const* d_in, const int* in_sizes, int n_in,
                              void* d_out, int out_size, void* d_ws, size_t ws_size,
                              hipStream_t stream) {
  const float* x_in   = (const float*)d_in[0];
  const float* wq_w   = (const float*)d_in[1];
  const float* wq_b   = (const float*)d_in[2];
  const float* wk_w   = (const float*)d_in[3];
  const float* wk_b   = (const float*)d_in[4];
  const float* wv_w   = (const float*)d_in[5];
  const float* wv_b   = (const float*)d_in[6];
  const float* wo_w   = (const float*)d_in[7];
  const float* wo_b   = (const float*)d_in[8];
  const float* sc_w   = (const float*)d_in[9];
  const float* sh1_w  = (const float*)d_in[10];
  const float* sh1_b  = (const float*)d_in[11];
  const float* sln1_g = (const float*)d_in[12];
  const float* sln1_b = (const float*)d_in[13];
  const float* sgf_w  = (const float*)d_in[14];
  const float* sgf_b  = (const float*)d_in[15];
  const float* sln2_g = (const float*)d_in[16];
  const float* sln2_b = (const float*)d_in[17];
  const float* swg_w  = (const float*)d_in[18];
  const float* ffn1_w = (const float*)d_in[19];
  const float* ffn1_b = (const float*)d_in[20];
  const float* ffn2_w = (const float*)d_in[21];
  const float* ffn2_b = (const float*)d_in[22];
  const float* n1_g   = (const float*)d_in[23];
  const float* n1_b   = (const float*)d_in[24];
  const float* n2_g   = (const float*)d_in[25];
  const float* n2_b   = (const float*)d_in[26];

  char* ws = (char*)d_ws;
  size_t off = 0;
  auto alloc = [&](size_t bytes) -> void* {
    void* p = ws + off;
    off += (bytes + 255) & ~(size_t)255;
    return p;
  };
  bf16*  xb    = (bf16*)alloc(8192ULL * 1024 * 2);
  float* P0    = (float*)alloc(8192ULL * 1024 * 4);
  float* P1    = (float*)alloc(8192ULL * 1024 * 4);
  bf16*  dT    = (bf16*)alloc(8192ULL * 1024 * 2);
  // double-buffered transposed weights (buf = layer & 1)
  bf16*  WqkvB = (bf16*)alloc(2ULL * 3072 * 1024 * 2);
  float* bqkvB = (float*)alloc(2ULL * 3072 * 4);
  bf16*  WoB   = (bf16*)alloc(2ULL * 1024 * 1024 * 2);
  bf16*  Wf1B  = (bf16*)alloc(2ULL * 1536 * 1024 * 2);
  bf16*  Wf2B  = (bf16*)alloc(2ULL * 1024 * 1536 * 2);
  bf16*  WsgfB = (bf16*)alloc(2ULL * 8192 * 256 * 2);
  bf16*  WswgB = (bf16*)alloc(2ULL * 4096 * 256 * 2);
  bf16*  Wsh1B = (bf16*)alloc(2ULL * 256 * 2048 * 2);
  bf16*  WscB  = (bf16*)alloc(2ULL * 32 * 1024 * 2);
  bf16*  qkvb  = (bf16*)alloc(8192ULL * 3072 * 2);
  bf16*  cbuf  = (bf16*)alloc(8192ULL * 32 * 2);
  float* hpre  = (float*)alloc(128ULL * 256 * 4);
  bf16*  hbb   = (bf16*)alloc(128ULL * 256 * 2);
  float* gpre  = (float*)alloc(128ULL * 8192 * 4);
  bf16*  gbb   = (bf16*)alloc(128ULL * 8192 * 2);
  bf16*  swb   = (bf16*)alloc(4096ULL * 4096 * 2);
  bf16*  avb   = (bf16*)alloc(8192ULL * 1024 * 2);
  bf16*  out1b = (bf16*)alloc(8192ULL * 1024 * 2);
  bf16*  f1b   = (bf16*)alloc(8192ULL * 1536 * 2);
  if (off > ws_size) {
    sentinel_k<<<1, 1, 0, stream>>>((float*)d_out);
    return;
  }

  cvt_f32_bf16_k<<<8192, 256, 0, stream>>>(x_in, xb, 8192LL * 1024);
  // prologue: transpose layer 0 into buf 0
  transpose_layer<<<10796, 256, 0, stream>>>(
      wq_w, wk_w, wv_w, wo_w, ffn1_w, ffn2_w, sgf_w, swg_w, sh1_w, sc_w,
      wq_b, wk_b, wv_b,
      WqkvB, WoB, Wf1B, Wf2B, WsgfB, WswgB, Wsh1B, WscB, bqkvB);

  for (int l = 0; l < 15; ++l) {
    const int cur = l & 1, nxt = cur ^ 1;
    const int lp = l + 1;
    bf16*  Wqkv = WqkvB + (size_t)cur * 3072 * 1024;
    float* bqkv = bqkvB + (size_t)cur * 3072;
    bf16*  Wo   = WoB   + (size_t)cur * 1024 * 1024;
    bf16*  Wf1  = Wf1B  + (size_t)cur * 1536 * 1024;
    bf16*  Wf2  = Wf2B  + (size_t)cur * 1024 * 1536;
    bf16*  Wsgf = WsgfB + (size_t)cur * 8192 * 256;
    bf16*  Wswg = WswgB + (size_t)cur * 4096 * 256;
    bf16*  Wsh1 = Wsh1B + (size_t)cur * 256 * 2048;
    bf16*  Wsc  = WscB  + (size_t)cur * 32 * 1024;

    const float* xc = (l == 0) ? x_in : ((l & 1) ? P0 : P1);
    float* Pout = (l & 1) ? P1 : P0;

    // megaA: QKV(BK=32, R21 optimum) || c || transpose(l+1)
    megaA<<<12460, 256, 0, stream>>>(
        xb, Wqkv, bqkv, qkvb, Wsc, cbuf, (l < 14) ? 1 : 0,
        wq_w + (size_t)lp * 1048576, wk_w + (size_t)lp * 1048576,
        wv_w + (size_t)lp * 1048576, wo_w + (size_t)lp * 1048576,
        ffn1_w + (size_t)lp * 1024 * 1536, ffn2_w + (size_t)lp * 1536 * 1024,
        sgf_w + (size_t)lp * 256 * 8192, swg_w + (size_t)lp * 256 * 4096,
        sh1_w + (size_t)lp * 2048 * 256, sc_w + (size_t)lp * 1024 * 32,
        wq_b + (size_t)lp * 1024, wk_b + (size_t)lp * 1024, wv_b + (size_t)lp * 1024,
        WqkvB + (size_t)nxt * 3072 * 1024, WoB + (size_t)nxt * 1024 * 1024,
        Wf1B + (size_t)nxt * 1536 * 1024, Wf2B + (size_t)nxt * 1024 * 1536,
        WsgfB + (size_t)nxt * 8192 * 256, WswgB + (size_t)nxt * 4096 * 256,
        Wsh1B + (size_t)nxt * 256 * 2048, WscB + (size_t)nxt * 32 * 1024,
        bqkvB + (size_t)nxt * 3072);
    // smolgen chain (MFMA wave16 path)
    gemm_wave16<1><<<128, 64, 0, stream>>>(cbuf, Wsh1, sh1_b + l * 256, hpre, 256, 2048);
    ln256_kernel<<<128, 256, 0, stream>>>(hpre, sln1_g + l * 256, sln1_b + l * 256, hbb);
    gemm_wave16<1><<<4096, 64, 0, stream>>>(hbb, Wsgf, sgf_b + (size_t)l * 8192, gpre,
                                            8192, 256);
    ln8192_kernel<<<128, 1024, 0, stream>>>(gpre, sln2_g + (size_t)l * 8192,
                                            sln2_b + (size_t)l * 8192, gbb);
    // sw gemm (BK=64 single-buffered)
    gemm64b<0, true, false><<<4096, 256, 0, stream>>>(gbb, Wswg, nullptr, nullptr,
                                                      swb, 4096, 4096, 256);
    // attention
    attn_kernel<<<4096, 256, 0, stream>>>(qkvb, swb, avb);
    // output projection + LN1
    gemm64b<0, true, true><<<2048, 256, 0, stream>>>(avb, Wo, wo_b + l * 1024,
                                                     nullptr, dT, 8192, 1024, 1024);
    ln_residual_kernel<<<8192, 256, 0, stream>>>(xc, dT, n1_g + l * 1024, n1_b + l * 1024,
                                                 Pout, out1b);
    // FFN + LN2
    gemm64b<2, true, true><<<3072, 256, 0, stream>>>(out1b, Wf1, ffn1_b + l * 1536,
                                                     nullptr, f1b, 8192, 1536, 1024);
    gemm64b<0, true, true><<<2048, 256, 0, stream>>>(f1b, Wf2, ffn2_b + l * 1024,
                                                     nullptr, dT, 8192, 1024, 1536);
    float* xnext = (l == 14) ? (float*)d_out : Pout;
    ln_residual_kernel<<<8192, 256, 0, stream>>>(Pout, dT, n2_g + l * 1024, n2_b + l * 1024,
                                                 xnext, xb);
  }
}